// Round 11
// baseline (23978.157 us; speedup 1.0000x reference)
//
#include <hip/hip_runtime.h>

// ---------------------------------------------------------------------------
// OmniAnomaly forward, round 11: pipelined multi-kernel, kernel-boundary sync.
// Superstep s: k_gru  [Q-GRU(s) wg0-63 || P-GRU(s-1) wg64-127]
//              k_lin  [Q dvec(s)      || P ddvec(s-1)]
//              k_tail [Q heads+reparam+flows(s) || P output head(s-1)]
// All plain cached loads/stores; coherence = kernel boundaries (HW flush).
// 32-row LDS A-slabs, 2-frag weight reuse, 512 thr / 8 waves per WG.
// B=256, W=128, IN=128, H=1024, Z=128, D=1024, OUT=128, K=3 flows
// ---------------------------------------------------------------------------

typedef __bf16 bf16;
typedef __bf16 bf16x8 __attribute__((ext_vector_type(8)));
typedef float  f32x4  __attribute__((ext_vector_type(4)));
typedef unsigned u32;

static constexpr int CB   = 256;
static constexpr int CW   = 128;
static constexpr int CIN  = 128;
static constexpr int CH   = 1024;
static constexpr int CZ   = 128;
static constexpr int CD   = 1024;
static constexpr int COUT = 128;

static constexpr int APITCH = 1160;                 // 1152 + 8 pad
static constexpr int GRU_SMEM = 32 * APITCH * 2;    // 74240 B (dynamic)
static constexpr int TPITCH = 1032;                 // 1024 + 8 pad (tail)

#define DEV static __device__ __forceinline__

DEV float sigmoidf_(float x) { return 1.0f / (1.0f + expf(-x)); }
DEV float softplusf_(float x) { return x > 20.0f ? x : log1pf(expf(x)); }
DEV bf16x8 ldfrag(const bf16* p) { return *reinterpret_cast<const bf16x8*>(p); }

#define MFMA(a, b, c) __builtin_amdgcn_mfma_f32_16x16x32_bf16((a), (b), (c), 0, 0, 0)

DEV u32 pk2(float a, float b) {
    union { bf16 h[2]; u32 u; } r;
    r.h[0] = (bf16)a; r.h[1] = (bf16)b;
    return r.u;
}

struct Prm {
    const float *eps_q, *eps_p;
    const float *bih_q, *bhh_q, *bd_q, *bmu_q, *bsig_q;
    const float *Wp, *bp, *up, *Wlg, *blg;
    const float *bih_p, *bhh_p, *bd_p, *bmu_p, *bsig_p;
    const bf16 *x_b, *Wih_qb, *Whh_qb, *Wd_qb, *Wmu_qb, *Wsg_qb;
    const bf16 *Wih_pb, *Whh_pb, *Wd_pb, *Wmu_pb, *Wsg_pb;
    float *e_f, *d_f;      // [2][CB][CH] fp32 masters (ping-pong)
    bf16 *e_b, *d_b;       // [2][CB][CH] bf16 shadows
    bf16 *dvec, *ddvec;    // [CB][CD]
    bf16 *zflow;           // [2][CB][CZ]  (z after flows; lin input)
    bf16 *ztlg;            // [2][CB][CZ]  (LGSSM out; P-GRU input)
    float *out_o, *out_mu, *out_lv;
};

// ---------------------------------------------------------------------------
__global__ void k_cvt(const float* __restrict__ src, bf16* __restrict__ dst, int n)
{
    int i = (blockIdx.x * blockDim.x + threadIdx.x) * 4;
    if (i < n) {
        float4 v = *reinterpret_cast<const float4*>(src + i);
        *reinterpret_cast<u32*>(dst + i)     = pk2(v.x, v.y);
        *reinterpret_cast<u32*>(dst + i + 2) = pk2(v.z, v.w);
    }
}

// ---------------------------------------------------------------------------
// GRU kernel: grid 128. wg<64: Q-GRU(tq); else P-GRU(tp).
// WG = 32 rows (slab=wgl>>3) x 128 e-cols (nsl=wgl&7); wave = 16 cols, 2 A-frags.
// ---------------------------------------------------------------------------
__launch_bounds__(512)
__global__ void k_gru(Prm p, int tq, int tp)
{
    extern __shared__ bf16 abuf[];
    const int wg = blockIdx.x, tid = threadIdx.x;
    const int lane = tid & 63, wave = tid >> 6;
    const bool isQ = wg < 64;
    if (isQ && tq >= CW) return;
    if (!isQ && tp < 0) return;
    const int wgl = isQ ? wg : wg - 64;
    const int r0 = (wgl >> 3) * 32;
    const int n0 = (wgl & 7) * 128;
    const int t  = isQ ? tq : tp;
    const int bi = t & 1;

    const bf16* head = isQ ? (p.x_b + (long)t * CIN)
                           : (p.ztlg + (size_t)bi * CB * CZ);
    const long  hrs  = isQ ? (long)CW * CIN : (long)CZ;
    const bf16* body = (isQ ? p.e_b : p.d_b) + (size_t)bi * CB * CH;

    {   // stage 32 rows x [head(128) | body(1024)]
        const int CHN = (CIN + CH) >> 3;   // 144
        for (int idx = tid; idx < 32 * CHN; idx += 512) {
            const int row = idx / CHN;
            const int k = (idx - row * CHN) * 8;
            bf16x8 v = (k < CIN) ? ldfrag(head + (long)(r0 + row) * hrs + k)
                                 : ldfrag(body + (long)(r0 + row) * CH + (k - CIN));
            *reinterpret_cast<bf16x8*>(abuf + (long)row * APITCH + k) = v;
        }
        __syncthreads();
    }

    const bf16*  Wih = isQ ? p.Wih_qb : p.Wih_pb;
    const bf16*  Whh = isQ ? p.Whh_qb : p.Whh_pb;
    const float* bih = isQ ? p.bih_q : p.bih_p;
    const float* bhh = isQ ? p.bhh_q : p.bhh_p;
    const float* efin = (isQ ? p.e_f : p.d_f) + (size_t)bi * CB * CH;
    float* efout = (isQ ? p.e_f : p.d_f) + (size_t)(bi ^ 1) * CB * CH;
    bf16*  ebout = (isQ ? p.e_b : p.d_b) + (size_t)(bi ^ 1) * CB * CH;

    const int lr = lane & 15, lkE = (lane >> 4) * 8;
    const int c = n0 + wave * 16 + lr;
    const bf16* a0p = abuf + (long)lr * APITCH;
    const bf16* a1p = abuf + (long)(16 + lr) * APITCH;

    f32x4 acc[2][4] = {};   // [frag][r,z,n_in,n_hh]
#pragma unroll 4
    for (int k = 0; k < CIN; k += 32) {
        bf16x8 a0 = *reinterpret_cast<const bf16x8*>(a0p + k + lkE);
        bf16x8 a1 = *reinterpret_cast<const bf16x8*>(a1p + k + lkE);
#pragma unroll
        for (int g = 0; g < 3; ++g) {
            bf16x8 b = ldfrag(Wih + ((long)g * CH + c) * CIN + k + lkE);
            const int grp = (g == 2) ? 2 : g;
            acc[0][grp] = MFMA(a0, b, acc[0][grp]);
            acc[1][grp] = MFMA(a1, b, acc[1][grp]);
        }
    }
#pragma unroll 4
    for (int k = 0; k < CH; k += 32) {
        bf16x8 a0 = *reinterpret_cast<const bf16x8*>(a0p + CIN + k + lkE);
        bf16x8 a1 = *reinterpret_cast<const bf16x8*>(a1p + CIN + k + lkE);
#pragma unroll
        for (int g = 0; g < 3; ++g) {
            bf16x8 b = ldfrag(Whh + ((long)g * CH + c) * CH + k + lkE);
            const int grp = (g == 2) ? 3 : g;
            acc[0][grp] = MFMA(a0, b, acc[0][grp]);
            acc[1][grp] = MFMA(a1, b, acc[1][grp]);
        }
    }

    const float b0r = bih[c] + bhh[c];
    const float b0z = bih[CH + c] + bhh[CH + c];
    const float bin = bih[2 * CH + c];
    const float bhn = bhh[2 * CH + c];
#pragma unroll
    for (int f = 0; f < 2; ++f) {
        const int rb = r0 + f * 16 + (lane >> 4) * 4;
#pragma unroll
        for (int i = 0; i < 4; ++i) {
            const int row = rb + i;
            float r = sigmoidf_(acc[f][0][i] + b0r);
            float u = sigmoidf_(acc[f][1][i] + b0z);
            float n = tanhf(acc[f][2][i] + bin + r * (acc[f][3][i] + bhn));
            float en = (1.0f - u) * n + u * efin[(long)row * CH + c];
            efout[(long)row * CH + c] = en;
            float vB = __shfl_xor(en, 1);
            if (!(lane & 1))
                *reinterpret_cast<u32*>(ebout + (long)row * CH + c) = pk2(en, vB);
        }
    }
}

// ---------------------------------------------------------------------------
// Linear kernel: grid 128. wg<64: Q dvec = [zflow|e]@Wd_q^T; else P ddvec.
// Same 32-row x 128-col WG tiling.
// ---------------------------------------------------------------------------
__launch_bounds__(512)
__global__ void k_lin(Prm p, int tq, int tp)
{
    extern __shared__ bf16 abuf[];
    const int wg = blockIdx.x, tid = threadIdx.x;
    const int lane = tid & 63, wave = tid >> 6;
    const bool isQ = wg < 64;
    if (isQ && tq >= CW) return;
    if (!isQ && tp < 0) return;
    const int wgl = isQ ? wg : wg - 64;
    const int r0 = (wgl >> 3) * 32;
    const int n0 = (wgl & 7) * 128;
    const int t  = isQ ? tq : tp;
    const int bi = t & 1;

    const int K1 = isQ ? CZ : 0;
    const int Ktot = K1 + CH;
    const bf16* head = isQ ? (p.zflow + (size_t)bi * CB * CZ) : nullptr;
    const bf16* body = (isQ ? p.e_b : p.d_b) + (size_t)(bi ^ 1) * CB * CH;

    {   // stage 32 rows x Ktot
        const int CHN = Ktot >> 3;
        for (int idx = tid; idx < 32 * CHN; idx += 512) {
            const int row = idx / CHN;
            const int k = (idx - row * CHN) * 8;
            bf16x8 v = (k < K1) ? ldfrag(head + (long)(r0 + row) * CZ + k)
                                : ldfrag(body + (long)(r0 + row) * CH + (k - K1));
            *reinterpret_cast<bf16x8*>(abuf + (long)row * APITCH + k) = v;
        }
        __syncthreads();
    }

    const bf16*  W    = isQ ? p.Wd_qb : p.Wd_pb;
    const float* bias = isQ ? p.bd_q : p.bd_p;
    bf16* outb = isQ ? p.dvec : p.ddvec;

    const int lr = lane & 15, lkE = (lane >> 4) * 8;
    const int c = n0 + wave * 16 + lr;
    const bf16* a0p = abuf + (long)lr * APITCH;
    const bf16* a1p = abuf + (long)(16 + lr) * APITCH;
    const bf16* wrow = W + (long)c * Ktot;

    f32x4 acc[2] = {};
#pragma unroll 4
    for (int k = 0; k < Ktot; k += 32) {
        bf16x8 a0 = *reinterpret_cast<const bf16x8*>(a0p + k + lkE);
        bf16x8 a1 = *reinterpret_cast<const bf16x8*>(a1p + k + lkE);
        bf16x8 b  = ldfrag(wrow + k + lkE);
        acc[0] = MFMA(a0, b, acc[0]);
        acc[1] = MFMA(a1, b, acc[1]);
    }

    const float bb = bias[c];
#pragma unroll
    for (int f = 0; f < 2; ++f) {
        const int rb = r0 + f * 16 + (lane >> 4) * 4;
#pragma unroll
        for (int i = 0; i < 4; ++i) {
            float v = acc[f][i] + bb;
            float vB = __shfl_xor(v, 1);
            if (!(lane & 1))
                *reinterpret_cast<u32*>(outb + (long)(rb + i) * CD + c) = pk2(v, vB);
        }
    }
}

// ---------------------------------------------------------------------------
// Tail kernel: grid 32. wg<16: Q slab (16 rows): both heads + reparam + flows.
// wg>=16: P slab: both heads + output. Wave = 16 cols; rows via frag mapping.
// ---------------------------------------------------------------------------
__launch_bounds__(512)
__global__ void k_tail(Prm p, int tq, int tp)
{
    __shared__ bf16 abuf[16 * TPITCH];
    __shared__ float zbuf[16 * CZ];
    const int wg = blockIdx.x, tid = threadIdx.x;
    const int lane = tid & 63, wave = tid >> 6;
    const bool isQ = wg < 16;
    if (isQ && tq >= CW) return;
    if (!isQ && tp < 0) return;
    const int slab = isQ ? wg : wg - 16;
    const int r0 = slab * 16;
    const int t  = isQ ? tq : tp;

    const bf16* A = isQ ? p.dvec : p.ddvec;
    {   // stage 16 rows x 1024
        for (int idx = tid; idx < 16 * (CD >> 3); idx += 512) {
            const int row = idx >> 7;           // CD>>3 = 128 chunks/row
            const int k = (idx & 127) * 8;
            *reinterpret_cast<bf16x8*>(abuf + (long)row * TPITCH + k) =
                ldfrag(A + (long)(r0 + row) * CD + k);
        }
        __syncthreads();
    }

    const bf16* Wm = isQ ? p.Wmu_qb : p.Wmu_pb;
    const bf16* Ws = isQ ? p.Wsg_qb : p.Wsg_pb;

    const int lr = lane & 15, lkE = (lane >> 4) * 8;
    const int c2 = wave * 16 + lr;
    const bf16* arow = abuf + (long)lr * TPITCH;
    const bf16* wm = Wm + (long)c2 * CD;
    const bf16* ws = Ws + (long)c2 * CD;

    f32x4 vm = {}, vs = {};
#pragma unroll 4
    for (int k = 0; k < CD; k += 32) {
        bf16x8 a  = *reinterpret_cast<const bf16x8*>(arow + k + lkE);
        vm = MFMA(a, ldfrag(wm + k + lkE), vm);
        vs = MFMA(a, ldfrag(ws + k + lkE), vs);
    }

#pragma unroll
    for (int i = 0; i < 4; ++i) {
        const int lrow = (lane >> 4) * 4 + i;
        const int row = r0 + lrow;
        if (isQ) {
            float mu = vm[i] + p.bmu_q[c2];
            float lv = softplusf_(vs[i] + p.bsig_q[c2]);
            float e  = p.eps_q[(size_t)row * CW * CZ + (size_t)t * CZ + c2];
            float z  = mu + expf(0.5f * lv) * e;
            p.out_mu[(size_t)row * CW * CZ + (size_t)t * CZ + c2] = mu;
            p.out_lv[(size_t)row * CW * CZ + (size_t)t * CZ + c2] = lv;
            zbuf[lrow * CZ + c2] = z;
        } else {
            float m  = vm[i] + p.bmu_p[c2];
            float sg = softplusf_(vs[i] + p.bsig_p[c2]);
            float e  = p.eps_p[(size_t)row * CW * COUT + (size_t)t * COUT + c2];
            p.out_o[(size_t)row * CW * COUT + (size_t)t * COUT + c2] = m + sg * e;
        }
    }
    if (!isQ) return;

    // ---- planar flows + LGSSM on zbuf (16 rows x 128), fp32 ----
    __syncthreads();
    const int r = tid >> 5;            // 0..15
    const int c0 = (tid & 31) * 4;     // 0..124
    for (int kf = 0; kf < 3; ++kf) {
        float s0 = p.bp[kf * CZ + c0],     s1 = p.bp[kf * CZ + c0 + 1];
        float s2 = p.bp[kf * CZ + c0 + 2], s3 = p.bp[kf * CZ + c0 + 3];
        const float* w0 = p.Wp + ((long)kf * CZ + c0) * CZ;
#pragma unroll 8
        for (int j = 0; j < CZ; j += 4) {
            float4 z4 = *reinterpret_cast<const float4*>(&zbuf[r * CZ + j]);
            float4 a0 = *reinterpret_cast<const float4*>(w0 + j);
            float4 a1 = *reinterpret_cast<const float4*>(w0 + CZ + j);
            float4 a2 = *reinterpret_cast<const float4*>(w0 + 2 * CZ + j);
            float4 a3 = *reinterpret_cast<const float4*>(w0 + 3 * CZ + j);
            s0 += z4.x * a0.x + z4.y * a0.y + z4.z * a0.z + z4.w * a0.w;
            s1 += z4.x * a1.x + z4.y * a1.y + z4.z * a1.z + z4.w * a1.w;
            s2 += z4.x * a2.x + z4.y * a2.y + z4.z * a2.z + z4.w * a2.w;
            s3 += z4.x * a3.x + z4.y * a3.y + z4.z * a3.z + z4.w * a3.w;
        }
        const float uk = p.up[kf];
        __syncthreads();
        zbuf[r * CZ + c0]     += uk * tanhf(s0);
        zbuf[r * CZ + c0 + 1] += uk * tanhf(s1);
        zbuf[r * CZ + c0 + 2] += uk * tanhf(s2);
        zbuf[r * CZ + c0 + 3] += uk * tanhf(s3);
        __syncthreads();
    }
    float s0 = p.blg[c0], s1 = p.blg[c0 + 1], s2 = p.blg[c0 + 2], s3 = p.blg[c0 + 3];
    const float* w0 = p.Wlg + (long)c0 * CZ;
#pragma unroll 8
    for (int j = 0; j < CZ; j += 4) {
        float4 z4 = *reinterpret_cast<const float4*>(&zbuf[r * CZ + j]);
        float4 a0 = *reinterpret_cast<const float4*>(w0 + j);
        float4 a1 = *reinterpret_cast<const float4*>(w0 + CZ + j);
        float4 a2 = *reinterpret_cast<const float4*>(w0 + 2 * CZ + j);
        float4 a3 = *reinterpret_cast<const float4*>(w0 + 3 * CZ + j);
        s0 += z4.x * a0.x + z4.y * a0.y + z4.z * a0.z + z4.w * a0.w;
        s1 += z4.x * a1.x + z4.y * a1.y + z4.z * a1.z + z4.w * a1.w;
        s2 += z4.x * a2.x + z4.y * a2.y + z4.z * a2.z + z4.w * a2.w;
        s3 += z4.x * a3.x + z4.y * a3.y + z4.z * a3.z + z4.w * a3.w;
    }
    const int grow = r0 + r;
    bf16* zt = p.ztlg + ((size_t)(t & 1) * CB + grow) * CZ + c0;
    *reinterpret_cast<u32*>(zt)     = pk2(s0, s1);
    *reinterpret_cast<u32*>(zt + 2) = pk2(s2, s3);
    bf16* zf = p.zflow + ((size_t)((t + 1) & 1) * CB + grow) * CZ + c0;
    *reinterpret_cast<u32*>(zf)     = pk2(zbuf[r * CZ + c0],     zbuf[r * CZ + c0 + 1]);
    *reinterpret_cast<u32*>(zf + 2) = pk2(zbuf[r * CZ + c0 + 2], zbuf[r * CZ + c0 + 3]);
}

// ---------------------------------------------------------------------------
// Host driver
// ---------------------------------------------------------------------------
extern "C" void kernel_launch(void* const* d_in, const int* in_sizes, int n_in,
                              void* d_out, int out_size, void* d_ws, size_t ws_size,
                              hipStream_t stream)
{
    Prm p;
    const float* x      = (const float*)d_in[0];
    p.eps_q  = (const float*)d_in[1];
    p.eps_p  = (const float*)d_in[2];
    const float* Wih_q  = (const float*)d_in[3];
    const float* Whh_q  = (const float*)d_in[4];
    p.bih_q  = (const float*)d_in[5];
    p.bhh_q  = (const float*)d_in[6];
    const float* Wd_q   = (const float*)d_in[7];
    p.bd_q   = (const float*)d_in[8];
    const float* Wmu_q  = (const float*)d_in[9];
    p.bmu_q  = (const float*)d_in[10];
    const float* Wsig_q = (const float*)d_in[11];
    p.bsig_q = (const float*)d_in[12];
    p.Wp     = (const float*)d_in[13];
    p.bp     = (const float*)d_in[14];
    p.up     = (const float*)d_in[15];
    p.Wlg    = (const float*)d_in[16];
    p.blg    = (const float*)d_in[17];
    const float* Wih_p  = (const float*)d_in[18];
    const float* Whh_p  = (const float*)d_in[19];
    p.bih_p  = (const float*)d_in[20];
    p.bhh_p  = (const float*)d_in[21];
    const float* Wd_p   = (const float*)d_in[22];
    p.bd_p   = (const float*)d_in[23];
    const float* Wmu_p  = (const float*)d_in[24];
    p.bmu_p  = (const float*)d_in[25];
    const float* Wsig_p = (const float*)d_in[26];
    p.bsig_p = (const float*)d_in[27];

    p.out_o  = (float*)d_out;
    p.out_mu = p.out_o + (size_t)CB * CW * COUT;
    p.out_lv = p.out_mu + (size_t)CB * CW * CZ;

    char* wp_ = (char*)d_ws;
    auto carve = [&](size_t bytes) -> void* {
        void* q = (void*)wp_;
        wp_ += (bytes + 255) & ~(size_t)255;
        return q;
    };
    p.e_f   = (float*)carve((size_t)2 * CB * CH * 4);
    p.d_f   = (float*)carve((size_t)2 * CB * CH * 4);
    p.e_b   = (bf16*)carve((size_t)2 * CB * CH * 2);
    p.d_b   = (bf16*)carve((size_t)2 * CB * CH * 2);
    p.dvec  = (bf16*)carve((size_t)CB * CD * 2);
    p.ddvec = (bf16*)carve((size_t)CB * CD * 2);
    p.zflow = (bf16*)carve((size_t)2 * CB * CZ * 2);
    p.ztlg  = (bf16*)carve((size_t)2 * CB * CZ * 2);
    bf16* x_b    = (bf16*)carve((size_t)CB * CW * CIN * 2);
    bf16* Wih_qb = (bf16*)carve((size_t)3 * CH * CIN * 2);
    bf16* Whh_qb = (bf16*)carve((size_t)3 * CH * CH * 2);
    bf16* Wd_qb  = (bf16*)carve((size_t)CD * (CZ + CH) * 2);
    bf16* Wmu_qb = (bf16*)carve((size_t)CZ * CD * 2);
    bf16* Wsg_qb = (bf16*)carve((size_t)CZ * CD * 2);
    bf16* Wih_pb = (bf16*)carve((size_t)3 * CH * CZ * 2);
    bf16* Whh_pb = (bf16*)carve((size_t)3 * CH * CH * 2);
    bf16* Wd_pb  = (bf16*)carve((size_t)CD * CH * 2);
    bf16* Wmu_pb = (bf16*)carve((size_t)COUT * CD * 2);
    bf16* Wsg_pb = (bf16*)carve((size_t)COUT * CD * 2);
    p.x_b = x_b;       p.Wih_qb = Wih_qb; p.Whh_qb = Whh_qb;
    p.Wd_qb = Wd_qb;   p.Wmu_qb = Wmu_qb; p.Wsg_qb = Wsg_qb;
    p.Wih_pb = Wih_pb; p.Whh_pb = Whh_pb; p.Wd_pb = Wd_pb;
    p.Wmu_pb = Wmu_pb; p.Wsg_pb = Wsg_pb;

    // zero init: ping slot 0 of states; zflow slot 0 (z(-1)=0)
    hipMemsetAsync(p.e_f, 0, (size_t)CB * CH * 4, stream);
    hipMemsetAsync(p.d_f, 0, (size_t)CB * CH * 4, stream);
    hipMemsetAsync(p.e_b, 0, (size_t)CB * CH * 2, stream);
    hipMemsetAsync(p.d_b, 0, (size_t)CB * CH * 2, stream);
    hipMemsetAsync(p.zflow, 0, (size_t)CB * CZ * 2, stream);

    auto cvt = [&](const float* s, bf16* d, size_t n) {
        k_cvt<<<dim3((unsigned)((n / 4 + 255) / 256)), dim3(256), 0, stream>>>(s, d, (int)n);
    };
    cvt(x,      x_b,    (size_t)CB * CW * CIN);
    cvt(Wih_q,  Wih_qb, (size_t)3 * CH * CIN);
    cvt(Whh_q,  Whh_qb, (size_t)3 * CH * CH);
    cvt(Wd_q,   Wd_qb,  (size_t)CD * (CZ + CH));
    cvt(Wmu_q,  Wmu_qb, (size_t)CZ * CD);
    cvt(Wsig_q, Wsg_qb, (size_t)CZ * CD);
    cvt(Wih_p,  Wih_pb, (size_t)3 * CH * CZ);
    cvt(Whh_p,  Whh_pb, (size_t)3 * CH * CH);
    cvt(Wd_p,   Wd_pb,  (size_t)CD * CH);
    cvt(Wmu_p,  Wmu_pb, (size_t)COUT * CD);
    cvt(Wsig_p, Wsg_pb, (size_t)COUT * CD);

    // allow >64KB dynamic LDS for the GEMM kernels (idempotent, non-stream op)
    hipFuncSetAttribute((const void*)k_gru,
                        hipFuncAttributeMaxDynamicSharedMemorySize, GRU_SMEM);
    hipFuncSetAttribute((const void*)k_lin,
                        hipFuncAttributeMaxDynamicSharedMemorySize, GRU_SMEM);

    // pipelined supersteps: s carries Q(t=s) and P(t=s-1)
    for (int s = 0; s <= CW; ++s) {
        k_gru<<<dim3(128), dim3(512), GRU_SMEM, stream>>>(p, s, s - 1);
        k_lin<<<dim3(128), dim3(512), GRU_SMEM, stream>>>(p, s, s - 1);
        k_tail<<<dim3(32), dim3(512), 0, stream>>>(p, s, s - 1);
    }
}

// Round 12
// 10683.218 us; speedup vs baseline: 2.2445x; 2.2445x over previous
//
#include <hip/hip_runtime.h>

// ---------------------------------------------------------------------------
// OmniAnomaly forward, round 12: r8 structure + cached-unique-address reads.
// Identical tiling/barriers to r8 (proven, 9.7ms). ONE change: all cross-WG
// buffers are per-timestep histories; cross-WG READS are plain cached loads
// at never-before-touched addresses (fresh by construction: producer's
// drained uncached store is at MALL; consumer L1/L2 never saw the line).
// Cross-WG WRITES stay relaxed agent-scope (uncached, ~2MB/step).
// Fallback (ws < 340MB): depth-2 ping-pong + uncached reads == r8 exactly.
// B=256, W=128, IN=128, H=1024, Z=128, D=1024, OUT=128, K=3 flows
// ---------------------------------------------------------------------------

typedef __bf16 bf16;
typedef __bf16 bf16x4 __attribute__((ext_vector_type(4)));
typedef __bf16 bf16x8 __attribute__((ext_vector_type(8)));
typedef float  f32x4  __attribute__((ext_vector_type(4)));
typedef unsigned long long u64;
typedef unsigned u32;

static constexpr int CB   = 256;
static constexpr int CW   = 128;
static constexpr int CIN  = 128;
static constexpr int CH   = 1024;
static constexpr int CZ   = 128;
static constexpr int CD   = 1024;
static constexpr int COUT = 128;

static constexpr int APITCH     = 1160;                      // 1152 + 8 pad
static constexpr int ABUF_BYTES = 16 * APITCH * 2;           // 37120
static constexpr int REDN       = 8 * 16 * 17;
static constexpr int RED2_BYTES = 2 * REDN * 4;              // 17408
static constexpr int FLOW_BYTES = (2 * CZ + 2 * 2 * CZ) * 4; // 3072
static constexpr int SMEM_BYTES = ABUF_BYTES + RED2_BYTES + FLOW_BYTES; // 57600

#define DEV static __device__ __forceinline__

DEV float sigmoidf_(float x) { return 1.0f / (1.0f + expf(-x)); }
DEV float softplusf_(float x) { return x > 20.0f ? x : log1pf(expf(x)); }
DEV bf16x8 ldfrag(const bf16* p) { return *reinterpret_cast<const bf16x8*>(p); }

#define MFMA(a, b, c) __builtin_amdgcn_mfma_f32_16x16x32_bf16((a), (b), (c), 0, 0, 0)

// ---- relaxed agent-scope helpers (uncached path) ----
DEV u64 lda8(const void* p) {
    return __hip_atomic_load((const u64*)p, __ATOMIC_RELAXED, __HIP_MEMORY_SCOPE_AGENT);
}
DEV u32 lda4(const void* p) {
    return __hip_atomic_load((const u32*)p, __ATOMIC_RELAXED, __HIP_MEMORY_SCOPE_AGENT);
}
DEV void sta4(void* p, u32 v) {
    __hip_atomic_store((u32*)p, v, __ATOMIC_RELAXED, __HIP_MEMORY_SCOPE_AGENT);
}
DEV bf16x8 ld_act16(const bf16* p) {
    union { u64 u[2]; bf16x8 v; } r;
    r.u[0] = lda8(p);
    r.u[1] = lda8((const char*)p + 8);
    return r.v;
}
DEV u32 pk2(float a, float b) {
    union { bf16 h[2]; u32 u; } r;
    r.h[0] = (bf16)a; r.h[1] = (bf16)b;
    return r.u;
}

struct Prm {
    const float *eps_q, *eps_p;
    const float *bih_q, *bhh_q, *bd_q, *bmu_q, *bsig_q;
    const float *Wp, *bp, *up, *Wlg, *blg;
    const float *bih_p, *bhh_p, *bd_p, *bmu_p, *bsig_p;
    const bf16 *x_b, *Wih_qb, *Whh_qb, *Wd_qb, *Wmu_qb, *Wsg_qb;
    const bf16 *Wih_pb, *Whh_pb, *Wd_pb, *Wmu_pb, *Wsg_pb;
    float *e_f0, *e_f1, *d_f0, *d_f1;   // fp32 masters (same-WG, cached)
    bf16 *e_h, *d_h;        // [(big?129:2)][CB][CH]  slot t = state entering step t
    bf16 *dvec_h, *ddvec_h; // [(big?128:1)][CB][CD]
    float *ztmp_h;          // [(big?128:1)][CB][CZ]
    bf16 *zflow_h;          // [(big?129:2)][CB][CZ]  slot t = z entering step t
    bf16 *ztlg_h;           // [(big?128:2)][CB][CZ]
    u32 *barQ, *barP, *zbar;
    float *out_o, *out_mu, *out_lv;
    int big;
};

// Per-half fence-free barrier over 128 WGs (r8-proven).
DEV void gbar_h(u32* bar, int wgl, u32 k)
{
    asm volatile("s_waitcnt vmcnt(0)" ::: "memory");
    __syncthreads();
    if (threadIdx.x == 0)
        __hip_atomic_store(&bar[wgl], k, __ATOMIC_RELAXED, __HIP_MEMORY_SCOPE_AGENT);
    if (threadIdx.x < 128) {
        while (__hip_atomic_load(&bar[threadIdx.x], __ATOMIC_RELAXED,
                                 __HIP_MEMORY_SCOPE_AGENT) < k)
            __builtin_amdgcn_s_sleep(1);
    }
    __syncthreads();
}

// ---------------------------------------------------------------------------
__global__ void k_cvt(const float* __restrict__ src, bf16* __restrict__ dst, int n)
{
    int i = (blockIdx.x * blockDim.x + threadIdx.x) * 4;
    if (i < n) {
        float4 v = *reinterpret_cast<const float4*>(src + i);
        *reinterpret_cast<u32*>(dst + i)     = pk2(v.x, v.y);
        *reinterpret_cast<u32*>(dst + i + 2) = pk2(v.z, v.w);
    }
}

// ---------------------------------------------------------------------------
// Stage slab rows [r0,+16) x [head(K1) | body(CH)] into abuf, per-source
// cached/uncached mode.
// ---------------------------------------------------------------------------
DEV void stage_act(bf16* abuf, int tid, int r0,
                   const bf16* head, long hs, int K1, bool hc,
                   const bf16* body, long bs, bool bc)
{
    const int CHN = (K1 + CH) >> 3;
    const int TOT = 16 * CHN;
    for (int idx = tid; idx < TOT; idx += 512) {
        const int row = idx / CHN;
        const int k = (idx - row * CHN) * 8;
        bf16x8 v;
        if (k < K1) {
            const bf16* s = head + (long)(r0 + row) * hs + k;
            v = hc ? ldfrag(s) : ld_act16(s);
        } else {
            const bf16* s = body + (long)(r0 + row) * bs + (k - K1);
            v = bc ? ldfrag(s) : ld_act16(s);
        }
        *reinterpret_cast<bf16x8*>(abuf + (long)row * APITCH + k) = v;
    }
    __syncthreads();
}

// ---------------------------------------------------------------------------
// GRU compute from staged LDS acts (r8 verbatim).
// ---------------------------------------------------------------------------
DEV void gru_compute(const bf16* abuf, int r0, int n0, int lane, int wave,
                     const bf16* __restrict__ Wih, const bf16* __restrict__ Whh,
                     const float* __restrict__ bih, const float* __restrict__ bhh,
                     const float* __restrict__ Efin,
                     float* __restrict__ Efo, bf16* __restrict__ Ebo)
{
    const int lr = lane & 15, lkE = (lane >> 4) * 8;
    const int c = n0 + wave * 16 + lr;
    const bf16* arow = abuf + (long)lr * APITCH;

    f32x4 acc[4] = {};
#pragma unroll 4
    for (int k = 0; k < CIN; k += 32) {
        bf16x8 a = *reinterpret_cast<const bf16x8*>(arow + k + lkE);
#pragma unroll
        for (int g = 0; g < 3; ++g) {
            bf16x8 b = ldfrag(Wih + ((long)g * CH + c) * CIN + k + lkE);
            const int grp = (g == 2) ? 2 : g;
            acc[grp] = MFMA(a, b, acc[grp]);
        }
    }
#pragma unroll 4
    for (int k = 0; k < CH; k += 32) {
        bf16x8 a = *reinterpret_cast<const bf16x8*>(arow + CIN + k + lkE);
#pragma unroll
        for (int g = 0; g < 3; ++g) {
            bf16x8 b = ldfrag(Whh + ((long)g * CH + c) * CH + k + lkE);
            const int grp = (g == 2) ? 3 : g;
            acc[grp] = MFMA(a, b, acc[grp]);
        }
    }

    const float b0r = bih[c] + bhh[c];
    const float b0z = bih[CH + c] + bhh[CH + c];
    const float bin = bih[2 * CH + c];
    const float bhn = bhh[2 * CH + c];
    const int rbase = r0 + (lane >> 4) * 4;
#pragma unroll
    for (int i = 0; i < 4; ++i) {
        const int row = rbase + i;
        float r = sigmoidf_(acc[0][i] + b0r);
        float u = sigmoidf_(acc[1][i] + b0z);
        float n = tanhf(acc[2][i] + bin + r * (acc[3][i] + bhn));
        float en = (1.0f - u) * n + u * Efin[(long)row * CH + c];
        Efo[(long)row * CH + c] = en;
        float vB = __shfl_xor(en, 1);
        if (!(lane & 1))
            sta4(Ebo + (long)row * CH + c, pk2(en, vB));
    }
}

// ---------------------------------------------------------------------------
DEV void lin_compute(const bf16* abuf, int r0, int n0, int lane, int wave, int Ktot,
                     const bf16* __restrict__ W,
                     const float* __restrict__ bias, bf16* __restrict__ Out)
{
    const int lr = lane & 15, lkE = (lane >> 4) * 8;
    const int c = n0 + wave * 16 + lr;
    const bf16* arow = abuf + (long)lr * APITCH;
    const bf16* wrow = W + (long)c * Ktot;

    f32x4 acc = {};
#pragma unroll 4
    for (int k = 0; k < CH; k += 32) {
        bf16x8 a = *reinterpret_cast<const bf16x8*>(arow + (Ktot - CH) + k + lkE);
        bf16x8 b = ldfrag(wrow + (Ktot - CH) + k + lkE);
        acc = MFMA(a, b, acc);
    }
    if (Ktot > CH) {
#pragma unroll 4
        for (int k = 0; k < CZ; k += 32) {
            bf16x8 a = *reinterpret_cast<const bf16x8*>(arow + k + lkE);
            bf16x8 b = ldfrag(wrow + k + lkE);
            acc = MFMA(a, b, acc);
        }
    }

    const float bb = bias[c];
    const int rbase = r0 + (lane >> 4) * 4;
#pragma unroll
    for (int i = 0; i < 4; ++i) {
        float v = acc[i] + bb;
        float vB = __shfl_xor(v, 1);
        if (!(lane & 1))
            sta4(Out + (long)(rbase + i) * CD + c, pk2(v, vB));
    }
}

// ---------------------------------------------------------------------------
// Two-head tail (r8 structure; A read cached in big mode).
// ---------------------------------------------------------------------------
template <int MODE>
DEV void phase_tail2(const Prm& p, int t, int wgl, int tid, int lane, int wave,
                     float* Ra, float* Rs, const bf16* __restrict__ A,
                     float* __restrict__ ztmp,
                     const bf16* __restrict__ Wa, const bf16* __restrict__ Wb,
                     const float* __restrict__ ba, const float* __restrict__ bb)
{
    const int lr = lane & 15, lkE = (lane >> 4) * 8;
    const int mb = (wgl >> 3) << 4;
    const int nb = (wgl & 7) << 4;
    f32x4 am = {}, as = {};
    const int k0 = wave * 128;
    if (p.big) {
#pragma unroll
        for (int kk = 0; kk < 128; kk += 32) {
            const int k = k0 + kk;
            bf16x8 a  = ldfrag(A + (long)(mb + lr) * CD + k + lkE);
            bf16x8 bm = ldfrag(Wa + (long)(nb + lr) * CD + k + lkE);
            bf16x8 bs = ldfrag(Wb + (long)(nb + lr) * CD + k + lkE);
            am = MFMA(a, bm, am);
            as = MFMA(a, bs, as);
        }
    } else {
#pragma unroll
        for (int kk = 0; kk < 128; kk += 32) {
            const int k = k0 + kk;
            bf16x8 a  = ld_act16(A + (long)(mb + lr) * CD + k + lkE);
            bf16x8 bm = ldfrag(Wa + (long)(nb + lr) * CD + k + lkE);
            bf16x8 bs = ldfrag(Wb + (long)(nb + lr) * CD + k + lkE);
            am = MFMA(a, bm, am);
            as = MFMA(a, bs, as);
        }
    }
    __syncthreads();
#pragma unroll
    for (int i = 0; i < 4; ++i) {
        Ra[(wave * 16 + (lane >> 4) * 4 + i) * 17 + lr] = am[i];
        Rs[(wave * 16 + (lane >> 4) * 4 + i) * 17 + lr] = as[i];
    }
    __syncthreads();
    if (tid < 256) {
        const int trow = tid >> 4, tcol = tid & 15;
        float vm = 0.f, vs = 0.f;
#pragma unroll
        for (int w = 0; w < 8; ++w) {
            vm += Ra[(w * 16 + trow) * 17 + tcol];
            vs += Rs[(w * 16 + trow) * 17 + tcol];
        }
        const int row = mb + trow, col = nb + tcol;
        if constexpr (MODE == 0) {
            float mu = vm + ba[col];
            float lv = softplusf_(vs + bb[col]);
            float e  = p.eps_q[(long)row * CW * CZ + (long)t * CZ + col];
            float z  = mu + expf(0.5f * lv) * e;
            p.out_mu[(long)row * CW * CZ + (long)t * CZ + col] = mu;
            p.out_lv[(long)row * CW * CZ + (long)t * CZ + col] = lv;
            sta4(ztmp + (long)row * CZ + col, __float_as_uint(z));
        } else {
            float m  = vm + ba[col];
            float sg = softplusf_(vs + bb[col]);
            float e  = p.eps_p[(long)row * CW * COUT + (long)t * COUT + col];
            p.out_o[(long)row * CW * COUT + (long)t * COUT + col] = m + sg * e;
        }
    }
}

// ---------------------------------------------------------------------------
// Planar flows + LGSSM (r8 structure; ztmp read cached in big mode).
// ---------------------------------------------------------------------------
DEV void phase_flows2(const Prm& p, int wgl, int tid, int t, float* zl, float* ps,
                      const float* __restrict__ ztmp,
                      bf16* __restrict__ ztlg, bf16* __restrict__ zflow_next)
{
    const int rg = tid >> 8;
    const int sub = tid & 255;
    const int c = sub & 127, half = sub >> 7;
    const int row = wgl * 2 + rg;
    float* zrow = zl + rg * CZ;
    float* pall = ps + rg * 2 * CZ;

    if (half == 0)
        zrow[c] = p.big ? ztmp[(long)row * CZ + c]
                        : __uint_as_float(lda4(ztmp + (long)row * CZ + c));
    __syncthreads();

#pragma unroll 1
    for (int kf = 0; kf < 3; ++kf) {
        const float* wr = p.Wp + ((long)kf * CZ + c) * CZ + half * 64;
        const float* zh = zrow + half * 64;
        float s = 0.f;
#pragma unroll
        for (int j = 0; j < 64; j += 4) {
            float4 w = *reinterpret_cast<const float4*>(wr + j);
            s += zh[j] * w.x + zh[j + 1] * w.y + zh[j + 2] * w.z + zh[j + 3] * w.w;
        }
        pall[half * CZ + c] = s;
        __syncthreads();
        if (half == 0) {
            float sf = pall[c] + pall[CZ + c] + p.bp[kf * CZ + c];
            zrow[c] += p.up[kf] * tanhf(sf);
        }
        __syncthreads();
    }
    {
        const float* wr = p.Wlg + (long)c * CZ + half * 64;
        const float* zh = zrow + half * 64;
        float s = 0.f;
#pragma unroll
        for (int j = 0; j < 64; j += 4) {
            float4 w = *reinterpret_cast<const float4*>(wr + j);
            s += zh[j] * w.x + zh[j + 1] * w.y + zh[j + 2] * w.z + zh[j + 3] * w.w;
        }
        pall[half * CZ + c] = s;
        __syncthreads();
        if (half == 0) {
            float zt = pall[c] + pall[CZ + c] + p.blg[c];
            float ztB = __shfl_xor(zt, 1);
            if (!(c & 1)) {
                sta4(ztlg + (long)row * CZ + c, pk2(zt, ztB));
                sta4(zflow_next + (long)row * CZ + c, pk2(zrow[c], zrow[c + 1]));
            }
        }
    }
}

// ---------------------------------------------------------------------------
// Mega kernel (r8 structure): 512 thr, r0=(wgl>>3)*16, n0=(wgl&7)*128.
// ---------------------------------------------------------------------------
__launch_bounds__(512)
__global__ void mega(Prm p)
{
    extern __shared__ char smem[];
    bf16*  abuf = (bf16*)smem;
    float* Ra   = (float*)(smem + ABUF_BYTES);
    float* Rs   = Ra + REDN;
    float* ZLp  = (float*)(smem + ABUF_BYTES + RED2_BYTES);
    float* PSp  = ZLp + 2 * CZ;

    const int wg = blockIdx.x, tid = threadIdx.x;
    const int lane = tid & 63, wave = tid >> 6;
    const bool isQ = wg < 128;
    const int wgl = isQ ? wg : wg - 128;
    const int r0 = (wgl >> 3) * 16;
    const int n0 = (wgl & 7) * 128;
    const bool big = p.big != 0;
    const size_t SH = (size_t)CB * CH;
    const size_t SD = (size_t)CB * CD;
    const size_t SZ = (size_t)CB * CZ;

    if (isQ) {
        u32 bk = 0;
#pragma unroll 1
        for (int t = 0; t < CW; ++t) {
            const int sIn  = big ? t : (t & 1);
            const int sOut = big ? (t + 1) : ((t + 1) & 1);
            const int sT   = big ? t : 0;
            const float* ef_i = (t & 1) ? p.e_f1 : p.e_f0;
            float*       ef_o = (t & 1) ? p.e_f0 : p.e_f1;

            // Q1: GRU encoder — reads e_h[sIn], writes e_h[sOut]
            stage_act(abuf, tid, r0, p.x_b + (long)t * CIN, (long)CW * CIN, CIN, true,
                      p.e_h + (size_t)sIn * SH, CH, big);
            gru_compute(abuf, r0, n0, lane, wave, p.Wih_qb, p.Whh_qb,
                        p.bih_q, p.bhh_q, ef_i, ef_o, p.e_h + (size_t)sOut * SH);
            gbar_h(p.barQ, wgl, ++bk);
            // Q2: d = [zflow[t] | e(t)] @ Wd_q^T
            stage_act(abuf, tid, r0, p.zflow_h + (size_t)sIn * SZ, CZ, CZ, big,
                      p.e_h + (size_t)sOut * SH, CH, big);
            lin_compute(abuf, r0, n0, lane, wave, CZ + CH, p.Wd_qb, p.bd_q,
                        p.dvec_h + (size_t)sT * SD);
            gbar_h(p.barQ, wgl, ++bk);
            // Q3: mu / lv / reparam z
            phase_tail2<0>(p, t, wgl, tid, lane, wave, Ra, Rs,
                           p.dvec_h + (size_t)sT * SD, p.ztmp_h + (size_t)sT * SZ,
                           p.Wmu_qb, p.Wsg_qb, p.bmu_q, p.bsig_q);
            gbar_h(p.barQ, wgl, ++bk);
            // Q4: flows + LGSSM — writes ztlg[t], zflow[t+1]
            phase_flows2(p, wgl, tid, t, ZLp, PSp,
                         p.ztmp_h + (size_t)sT * SZ,
                         p.ztlg_h + (size_t)(big ? t : (t & 1)) * SZ,
                         p.zflow_h + (size_t)sOut * SZ);
            asm volatile("s_waitcnt vmcnt(0)" ::: "memory");
            __syncthreads();
            if (tid == 0)
                __hip_atomic_store(&p.zbar[wgl], (u32)(t + 1),
                                   __ATOMIC_RELAXED, __HIP_MEMORY_SCOPE_AGENT);
            __syncthreads();
        }
    } else {
        u32 bk = 0;
#pragma unroll 1
        for (int t = 0; t < CW; ++t) {
            if (tid < 128) {
                while (__hip_atomic_load(&p.zbar[tid], __ATOMIC_RELAXED,
                                         __HIP_MEMORY_SCOPE_AGENT) < (u32)(t + 1))
                    __builtin_amdgcn_s_sleep(2);
            }
            __syncthreads();

            const int sIn  = big ? t : (t & 1);
            const int sOut = big ? (t + 1) : ((t + 1) & 1);
            const int sT   = big ? t : 0;
            const float* df_i = (t & 1) ? p.d_f1 : p.d_f0;
            float*       df_o = (t & 1) ? p.d_f0 : p.d_f1;

            // P1: GRU decoder — reads ztlg[t], d_h[sIn]; writes d_h[sOut]
            stage_act(abuf, tid, r0,
                      p.ztlg_h + (size_t)(big ? t : (t & 1)) * SZ, CZ, CZ, big,
                      p.d_h + (size_t)sIn * SH, CH, big);
            gru_compute(abuf, r0, n0, lane, wave, p.Wih_pb, p.Whh_pb,
                        p.bih_p, p.bhh_p, df_i, df_o, p.d_h + (size_t)sOut * SH);
            gbar_h(p.barP, wgl, ++bk);
            // P2: dd = d(t) @ Wd_p^T
            stage_act(abuf, tid, r0, nullptr, 0, 0, false,
                      p.d_h + (size_t)sOut * SH, CH, big);
            lin_compute(abuf, r0, n0, lane, wave, CH, p.Wd_pb, p.bd_p,
                        p.ddvec_h + (size_t)sT * SD);
            gbar_h(p.barP, wgl, ++bk);
            // P3: output head
            phase_tail2<1>(p, t, wgl, tid, lane, wave, Ra, Rs,
                           p.ddvec_h + (size_t)sT * SD, nullptr,
                           p.Wmu_pb, p.Wsg_pb, p.bmu_p, p.bsig_p);
        }
    }
}

// ---------------------------------------------------------------------------
// Host driver
// ---------------------------------------------------------------------------
extern "C" void kernel_launch(void* const* d_in, const int* in_sizes, int n_in,
                              void* d_out, int out_size, void* d_ws, size_t ws_size,
                              hipStream_t stream)
{
    Prm p;
    const float* x      = (const float*)d_in[0];
    p.eps_q  = (const float*)d_in[1];
    p.eps_p  = (const float*)d_in[2];
    const float* Wih_q  = (const float*)d_in[3];
    const float* Whh_q  = (const float*)d_in[4];
    p.bih_q  = (const float*)d_in[5];
    p.bhh_q  = (const float*)d_in[6];
    const float* Wd_q   = (const float*)d_in[7];
    p.bd_q   = (const float*)d_in[8];
    const float* Wmu_q  = (const float*)d_in[9];
    p.bmu_q  = (const float*)d_in[10];
    const float* Wsig_q = (const float*)d_in[11];
    p.bsig_q = (const float*)d_in[12];
    p.Wp     = (const float*)d_in[13];
    p.bp     = (const float*)d_in[14];
    p.up     = (const float*)d_in[15];
    p.Wlg    = (const float*)d_in[16];
    p.blg    = (const float*)d_in[17];
    const float* Wih_p  = (const float*)d_in[18];
    const float* Whh_p  = (const float*)d_in[19];
    p.bih_p  = (const float*)d_in[20];
    p.bhh_p  = (const float*)d_in[21];
    const float* Wd_p   = (const float*)d_in[22];
    p.bd_p   = (const float*)d_in[23];
    const float* Wmu_p  = (const float*)d_in[24];
    p.bmu_p  = (const float*)d_in[25];
    const float* Wsig_p = (const float*)d_in[26];
    p.bsig_p = (const float*)d_in[27];

    p.out_o  = (float*)d_out;
    p.out_mu = p.out_o + (size_t)CB * CW * COUT;
    p.out_lv = p.out_mu + (size_t)CB * CW * CZ;

    p.big = (ws_size >= (size_t)340 * 1024 * 1024) ? 1 : 0;
    const int NS = p.big ? (CW + 1) : 2;    // state slots
    const int NT = p.big ? CW : 1;          // per-step slots
    const int NZ = p.big ? CW : 2;          // ztlg slots

    char* wp_ = (char*)d_ws;
    auto carve = [&](size_t bytes) -> void* {
        void* q = (void*)wp_;
        wp_ += (bytes + 255) & ~(size_t)255;
        return q;
    };
    p.e_f0 = (float*)carve((size_t)CB * CH * 4);
    p.e_f1 = (float*)carve((size_t)CB * CH * 4);
    p.d_f0 = (float*)carve((size_t)CB * CH * 4);
    p.d_f1 = (float*)carve((size_t)CB * CH * 4);
    p.e_h     = (bf16*)carve((size_t)NS * CB * CH * 2);
    p.d_h     = (bf16*)carve((size_t)NS * CB * CH * 2);
    p.dvec_h  = (bf16*)carve((size_t)NT * CB * CD * 2);
    p.ddvec_h = (bf16*)carve((size_t)NT * CB * CD * 2);
    p.ztmp_h  = (float*)carve((size_t)NT * CB * CZ * 4);
    p.zflow_h = (bf16*)carve((size_t)NS * CB * CZ * 2);
    p.ztlg_h  = (bf16*)carve((size_t)NZ * CB * CZ * 2);
    p.barQ    = (u32*)carve(512);
    p.barP    = (u32*)carve(512);
    p.zbar    = (u32*)carve(512);
    bf16* x_b    = (bf16*)carve((size_t)CB * CW * CIN * 2);
    bf16* Wih_qb = (bf16*)carve((size_t)3 * CH * CIN * 2);
    bf16* Whh_qb = (bf16*)carve((size_t)3 * CH * CH * 2);
    bf16* Wd_qb  = (bf16*)carve((size_t)CD * (CZ + CH) * 2);
    bf16* Wmu_qb = (bf16*)carve((size_t)CZ * CD * 2);
    bf16* Wsg_qb = (bf16*)carve((size_t)CZ * CD * 2);
    bf16* Wih_pb = (bf16*)carve((size_t)3 * CH * CZ * 2);
    bf16* Whh_pb = (bf16*)carve((size_t)3 * CH * CH * 2);
    bf16* Wd_pb  = (bf16*)carve((size_t)CD * CH * 2);
    bf16* Wmu_pb = (bf16*)carve((size_t)COUT * CD * 2);
    bf16* Wsg_pb = (bf16*)carve((size_t)COUT * CD * 2);
    p.x_b = x_b;       p.Wih_qb = Wih_qb; p.Whh_qb = Whh_qb;
    p.Wd_qb = Wd_qb;   p.Wmu_qb = Wmu_qb; p.Wsg_qb = Wsg_qb;
    p.Wih_pb = Wih_pb; p.Whh_pb = Whh_pb; p.Wd_pb = Wd_pb;
    p.Wmu_pb = Wmu_pb; p.Wsg_pb = Wsg_pb;

    // zero-init: slot 0 of states (e(-1)=d(-1)=0, z(-1)=0), masters, flags
    hipMemsetAsync(p.e_f0, 0, (size_t)CB * CH * 4, stream);
    hipMemsetAsync(p.d_f0, 0, (size_t)CB * CH * 4, stream);
    hipMemsetAsync(p.e_h, 0, (size_t)CB * CH * 2, stream);
    hipMemsetAsync(p.d_h, 0, (size_t)CB * CH * 2, stream);
    hipMemsetAsync(p.zflow_h, 0, (size_t)CB * CZ * 2, stream);
    hipMemsetAsync(p.barQ, 0, 512, stream);
    hipMemsetAsync(p.barP, 0, 512, stream);
    hipMemsetAsync(p.zbar, 0, 512, stream);

    auto cvt = [&](const float* s, bf16* d, size_t n) {
        k_cvt<<<dim3((unsigned)((n / 4 + 255) / 256)), dim3(256), 0, stream>>>(s, d, (int)n);
    };
    cvt(x,      x_b,    (size_t)CB * CW * CIN);
    cvt(Wih_q,  Wih_qb, (size_t)3 * CH * CIN);
    cvt(Whh_q,  Whh_qb, (size_t)3 * CH * CH);
    cvt(Wd_q,   Wd_qb,  (size_t)CD * (CZ + CH));
    cvt(Wmu_q,  Wmu_qb, (size_t)CZ * CD);
    cvt(Wsig_q, Wsg_qb, (size_t)CZ * CD);
    cvt(Wih_p,  Wih_pb, (size_t)3 * CH * CZ);
    cvt(Whh_p,  Whh_pb, (size_t)3 * CH * CH);
    cvt(Wd_p,   Wd_pb,  (size_t)CD * CH);
    cvt(Wmu_p,  Wmu_pb, (size_t)COUT * CD);
    cvt(Wsig_p, Wsg_pb, (size_t)COUT * CD);

    mega<<<dim3(256), dim3(512), SMEM_BYTES, stream>>>(p);
}

// Round 13
// 10356.669 us; speedup vs baseline: 2.3152x; 1.0315x over previous
//
#include <hip/hip_runtime.h>

// ---------------------------------------------------------------------------
// OmniAnomaly forward, round 13: r8 structure + WIDE coherent accesses.
// Identical tiling/barriers to r8 (9.7ms proven). ONE change: cross-WG data
// moves via plain global_load_dwordx4 / global_store_dword with "sc0 sc1"
// (device-coherent, L1/L2-bypass — same semantics as agent-scope atomics but
// TA-coalesced and 16B wide, vs the 4/8B uncoalesced __hip_atomic ops that
// capped r8 at ~341 GB/s effective).
// B=256, W=128, IN=128, H=1024, Z=128, D=1024, OUT=128, K=3 flows
// ---------------------------------------------------------------------------

typedef __bf16 bf16;
typedef __bf16 bf16x8 __attribute__((ext_vector_type(8)));
typedef float  f32x4  __attribute__((ext_vector_type(4)));
typedef unsigned long long u64;
typedef unsigned u32;

static constexpr int CB   = 256;
static constexpr int CW   = 128;
static constexpr int CIN  = 128;
static constexpr int CH   = 1024;
static constexpr int CZ   = 128;
static constexpr int CD   = 1024;
static constexpr int COUT = 128;

static constexpr int APITCH     = 1160;                      // 1152 + 8 pad
static constexpr int ABUF_BYTES = 16 * APITCH * 2;           // 37120
static constexpr int REDN       = 8 * 16 * 17;
static constexpr int RED2_BYTES = 2 * REDN * 4;              // 17408
static constexpr int FLOW_BYTES = (2 * CZ + 2 * 2 * CZ) * 4; // 3072
static constexpr int SMEM_BYTES = ABUF_BYTES + RED2_BYTES + FLOW_BYTES; // 57600

#define DEV static __device__ __forceinline__

DEV float sigmoidf_(float x) { return 1.0f / (1.0f + expf(-x)); }
DEV float softplusf_(float x) { return x > 20.0f ? x : log1pf(expf(x)); }
DEV bf16x8 ldfrag(const bf16* p) { return *reinterpret_cast<const bf16x8*>(p); }

#define MFMA(a, b, c) __builtin_amdgcn_mfma_f32_16x16x32_bf16((a), (b), (c), 0, 0, 0)

// ---- WIDE device-coherent accesses (sc0 sc1 = L1/L2-bypass, coalesced) ----
DEV bf16x8 ldsc16(const bf16* p) {
    bf16x8 v;
    asm volatile("global_load_dwordx4 %0, %1, off sc0 sc1\n\t"
                 "s_waitcnt vmcnt(0)"
                 : "=v"(v) : "v"(p) : "memory");
    return v;
}
DEV u32 ldsc4(const void* p) {
    u32 v;
    asm volatile("global_load_dword %0, %1, off sc0 sc1\n\t"
                 "s_waitcnt vmcnt(0)"
                 : "=v"(v) : "v"(p) : "memory");
    return v;
}
DEV void stsc4(void* p, u32 v) {
    asm volatile("global_store_dword %0, %1, off sc0 sc1"
                 :: "v"(p), "v"(v) : "memory");
}
DEV u32 pk2(float a, float b) {
    union { bf16 h[2]; u32 u; } r;
    r.h[0] = (bf16)a; r.h[1] = (bf16)b;
    return r.u;
}

struct Prm {
    const float *eps_q, *eps_p;
    const float *bih_q, *bhh_q, *bd_q, *bmu_q, *bsig_q;
    const float *Wp, *bp, *up, *Wlg, *blg;
    const float *bih_p, *bhh_p, *bd_p, *bmu_p, *bsig_p;
    const bf16 *x_b, *Wih_qb, *Whh_qb, *Wd_qb, *Wmu_qb, *Wsg_qb;
    const bf16 *Wih_pb, *Whh_pb, *Wd_pb, *Wmu_pb, *Wsg_pb;
    float *e_f0, *e_f1, *d_f0, *d_f1;   // fp32 masters (WG-private, cached)
    bf16 *e_b0, *e_b1, *d_b0, *d_b1;    // bf16 shadows (cross-WG, sc)
    float *ztmp_f;
    bf16 *dvec_b, *ddvec_b;
    bf16 *zflow;    // [2][CB][CZ]
    bf16 *ztlg;     // [2][CB][CZ]
    u32 *barQ, *barP, *zbar;
    float *out_o, *out_mu, *out_lv;
};

// Per-half fence-free barrier over 128 WGs (r8-proven).
DEV void gbar_h(u32* bar, int wgl, u32 k)
{
    asm volatile("s_waitcnt vmcnt(0)" ::: "memory");
    __syncthreads();
    if (threadIdx.x == 0)
        __hip_atomic_store(&bar[wgl], k, __ATOMIC_RELAXED, __HIP_MEMORY_SCOPE_AGENT);
    if (threadIdx.x < 128) {
        while (__hip_atomic_load(&bar[threadIdx.x], __ATOMIC_RELAXED,
                                 __HIP_MEMORY_SCOPE_AGENT) < k)
            __builtin_amdgcn_s_sleep(1);
    }
    __syncthreads();
}

// ---------------------------------------------------------------------------
__global__ void k_cvt(const float* __restrict__ src, bf16* __restrict__ dst, int n)
{
    int i = (blockIdx.x * blockDim.x + threadIdx.x) * 4;
    if (i < n) {
        float4 v = *reinterpret_cast<const float4*>(src + i);
        *reinterpret_cast<u32*>(dst + i)     = pk2(v.x, v.y);
        *reinterpret_cast<u32*>(dst + i + 2) = pk2(v.z, v.w);
    }
}

// ---------------------------------------------------------------------------
// Stage slab rows [r0,+16) x [head(K1) | body(CH)] into abuf.
// hc: head cached (input x) vs sc-coherent.
// ---------------------------------------------------------------------------
DEV void stage_act(bf16* abuf, int tid, int r0,
                   const bf16* head, long hs, int K1, bool hc,
                   const bf16* body, long bs)
{
    const int CHN = (K1 + CH) >> 3;
    const int TOT = 16 * CHN;
    for (int idx = tid; idx < TOT; idx += 512) {
        const int row = idx / CHN;
        const int k = (idx - row * CHN) * 8;
        bf16x8 v;
        if (k < K1) {
            const bf16* s = head + (long)(r0 + row) * hs + k;
            v = hc ? ldfrag(s) : ldsc16(s);
        } else {
            v = ldsc16(body + (long)(r0 + row) * bs + (k - K1));
        }
        *reinterpret_cast<bf16x8*>(abuf + (long)row * APITCH + k) = v;
    }
    __syncthreads();
}

// ---------------------------------------------------------------------------
// GRU compute from staged LDS acts (r8 verbatim; stores via stsc4).
// ---------------------------------------------------------------------------
DEV void gru_compute(const bf16* abuf, int r0, int n0, int lane, int wave,
                     const bf16* __restrict__ Wih, const bf16* __restrict__ Whh,
                     const float* __restrict__ bih, const float* __restrict__ bhh,
                     const float* __restrict__ Efin,
                     float* __restrict__ Efo, bf16* __restrict__ Ebo)
{
    const int lr = lane & 15, lkE = (lane >> 4) * 8;
    const int c = n0 + wave * 16 + lr;
    const bf16* arow = abuf + (long)lr * APITCH;

    f32x4 acc[4] = {};
#pragma unroll 4
    for (int k = 0; k < CIN; k += 32) {
        bf16x8 a = *reinterpret_cast<const bf16x8*>(arow + k + lkE);
#pragma unroll
        for (int g = 0; g < 3; ++g) {
            bf16x8 b = ldfrag(Wih + ((long)g * CH + c) * CIN + k + lkE);
            const int grp = (g == 2) ? 2 : g;
            acc[grp] = MFMA(a, b, acc[grp]);
        }
    }
#pragma unroll 4
    for (int k = 0; k < CH; k += 32) {
        bf16x8 a = *reinterpret_cast<const bf16x8*>(arow + CIN + k + lkE);
#pragma unroll
        for (int g = 0; g < 3; ++g) {
            bf16x8 b = ldfrag(Whh + ((long)g * CH + c) * CH + k + lkE);
            const int grp = (g == 2) ? 3 : g;
            acc[grp] = MFMA(a, b, acc[grp]);
        }
    }

    const float b0r = bih[c] + bhh[c];
    const float b0z = bih[CH + c] + bhh[CH + c];
    const float bin = bih[2 * CH + c];
    const float bhn = bhh[2 * CH + c];
    const int rbase = r0 + (lane >> 4) * 4;
#pragma unroll
    for (int i = 0; i < 4; ++i) {
        const int row = rbase + i;
        float r = sigmoidf_(acc[0][i] + b0r);
        float u = sigmoidf_(acc[1][i] + b0z);
        float n = tanhf(acc[2][i] + bin + r * (acc[3][i] + bhn));
        float en = (1.0f - u) * n + u * Efin[(long)row * CH + c];
        Efo[(long)row * CH + c] = en;
        float vB = __shfl_xor(en, 1);
        if (!(lane & 1))
            stsc4(Ebo + (long)row * CH + c, pk2(en, vB));
    }
}

// ---------------------------------------------------------------------------
DEV void lin_compute(const bf16* abuf, int r0, int n0, int lane, int wave, int Ktot,
                     const bf16* __restrict__ W,
                     const float* __restrict__ bias, bf16* __restrict__ Out)
{
    const int lr = lane & 15, lkE = (lane >> 4) * 8;
    const int c = n0 + wave * 16 + lr;
    const bf16* arow = abuf + (long)lr * APITCH;
    const bf16* wrow = W + (long)c * Ktot;

    f32x4 acc = {};
#pragma unroll 4
    for (int k = 0; k < CH; k += 32) {
        bf16x8 a = *reinterpret_cast<const bf16x8*>(arow + (Ktot - CH) + k + lkE);
        bf16x8 b = ldfrag(wrow + (Ktot - CH) + k + lkE);
        acc = MFMA(a, b, acc);
    }
    if (Ktot > CH) {
#pragma unroll 4
        for (int k = 0; k < CZ; k += 32) {
            bf16x8 a = *reinterpret_cast<const bf16x8*>(arow + k + lkE);
            bf16x8 b = ldfrag(wrow + k + lkE);
            acc = MFMA(a, b, acc);
        }
    }

    const float bb = bias[c];
    const int rbase = r0 + (lane >> 4) * 4;
#pragma unroll
    for (int i = 0; i < 4; ++i) {
        float v = acc[i] + bb;
        float vB = __shfl_xor(v, 1);
        if (!(lane & 1))
            stsc4(Out + (long)(rbase + i) * CD + c, pk2(v, vB));
    }
}

// ---------------------------------------------------------------------------
// Two-head tail (r8 structure; A read via wide sc loads).
// ---------------------------------------------------------------------------
template <int MODE>
DEV void phase_tail2(const Prm& p, int t, int wgl, int tid, int lane, int wave,
                     float* Ra, float* Rs, const bf16* __restrict__ A,
                     const bf16* __restrict__ Wa, const bf16* __restrict__ Wb,
                     const float* __restrict__ ba, const float* __restrict__ bb)
{
    const int lr = lane & 15, lkE = (lane >> 4) * 8;
    const int mb = (wgl >> 3) << 4;
    const int nb = (wgl & 7) << 4;
    f32x4 am = {}, as = {};
    const int k0 = wave * 128;
#pragma unroll
    for (int kk = 0; kk < 128; kk += 32) {
        const int k = k0 + kk;
        bf16x8 a  = ldsc16(A + (long)(mb + lr) * CD + k + lkE);
        bf16x8 bm = ldfrag(Wa + (long)(nb + lr) * CD + k + lkE);
        bf16x8 bs = ldfrag(Wb + (long)(nb + lr) * CD + k + lkE);
        am = MFMA(a, bm, am);
        as = MFMA(a, bs, as);
    }
    __syncthreads();
#pragma unroll
    for (int i = 0; i < 4; ++i) {
        Ra[(wave * 16 + (lane >> 4) * 4 + i) * 17 + lr] = am[i];
        Rs[(wave * 16 + (lane >> 4) * 4 + i) * 17 + lr] = as[i];
    }
    __syncthreads();
    if (tid < 256) {
        const int trow = tid >> 4, tcol = tid & 15;
        float vm = 0.f, vs = 0.f;
#pragma unroll
        for (int w = 0; w < 8; ++w) {
            vm += Ra[(w * 16 + trow) * 17 + tcol];
            vs += Rs[(w * 16 + trow) * 17 + tcol];
        }
        const int row = mb + trow, col = nb + tcol;
        if constexpr (MODE == 0) {
            float mu = vm + ba[col];
            float lv = softplusf_(vs + bb[col]);
            float e  = p.eps_q[(long)row * CW * CZ + (long)t * CZ + col];
            float z  = mu + expf(0.5f * lv) * e;
            p.out_mu[(long)row * CW * CZ + (long)t * CZ + col] = mu;
            p.out_lv[(long)row * CW * CZ + (long)t * CZ + col] = lv;
            stsc4(p.ztmp_f + (long)row * CZ + col, __float_as_uint(z));
        } else {
            float m  = vm + ba[col];
            float sg = softplusf_(vs + bb[col]);
            float e  = p.eps_p[(long)row * CW * COUT + (long)t * COUT + col];
            p.out_o[(long)row * CW * COUT + (long)t * COUT + col] = m + sg * e;
        }
    }
}

// ---------------------------------------------------------------------------
// Planar flows + LGSSM (r8 structure; sc accesses for cross-WG data).
// ---------------------------------------------------------------------------
DEV void phase_flows2(const Prm& p, int wgl, int tid, int t, float* zl, float* ps)
{
    const int rg = tid >> 8;
    const int sub = tid & 255;
    const int c = sub & 127, half = sub >> 7;
    const int row = wgl * 2 + rg;
    float* zrow = zl + rg * CZ;
    float* pall = ps + rg * 2 * CZ;

    if (half == 0)
        zrow[c] = __uint_as_float(ldsc4(p.ztmp_f + (long)row * CZ + c));
    __syncthreads();

#pragma unroll 1
    for (int kf = 0; kf < 3; ++kf) {
        const float* wr = p.Wp + ((long)kf * CZ + c) * CZ + half * 64;
        const float* zh = zrow + half * 64;
        float s = 0.f;
#pragma unroll
        for (int j = 0; j < 64; j += 4) {
            float4 w = *reinterpret_cast<const float4*>(wr + j);
            s += zh[j] * w.x + zh[j + 1] * w.y + zh[j + 2] * w.z + zh[j + 3] * w.w;
        }
        pall[half * CZ + c] = s;
        __syncthreads();
        if (half == 0) {
            float sf = pall[c] + pall[CZ + c] + p.bp[kf * CZ + c];
            zrow[c] += p.up[kf] * tanhf(sf);
        }
        __syncthreads();
    }
    {
        const float* wr = p.Wlg + (long)c * CZ + half * 64;
        const float* zh = zrow + half * 64;
        float s = 0.f;
#pragma unroll
        for (int j = 0; j < 64; j += 4) {
            float4 w = *reinterpret_cast<const float4*>(wr + j);
            s += zh[j] * w.x + zh[j + 1] * w.y + zh[j + 2] * w.z + zh[j + 3] * w.w;
        }
        pall[half * CZ + c] = s;
        __syncthreads();
        if (half == 0) {
            float zt = pall[c] + pall[CZ + c] + p.blg[c];
            float ztB = __shfl_xor(zt, 1);
            if (!(c & 1)) {
                stsc4(p.ztlg + ((size_t)(t & 1) * CB + row) * CZ + c, pk2(zt, ztB));
                stsc4(p.zflow + ((size_t)((t + 1) & 1) * CB + row) * CZ + c,
                      pk2(zrow[c], zrow[c + 1]));
            }
        }
    }
}

// ---------------------------------------------------------------------------
// Mega kernel (r8 structure): 512 thr, r0=(wgl>>3)*16, n0=(wgl&7)*128.
// ---------------------------------------------------------------------------
__launch_bounds__(512)
__global__ void mega(Prm p)
{
    extern __shared__ char smem[];
    bf16*  abuf = (bf16*)smem;
    float* Ra   = (float*)(smem + ABUF_BYTES);
    float* Rs   = Ra + REDN;
    float* ZLp  = (float*)(smem + ABUF_BYTES + RED2_BYTES);
    float* PSp  = ZLp + 2 * CZ;

    const int wg = blockIdx.x, tid = threadIdx.x;
    const int lane = tid & 63, wave = tid >> 6;
    const bool isQ = wg < 128;
    const int wgl = isQ ? wg : wg - 128;
    const int r0 = (wgl >> 3) * 16;
    const int n0 = (wgl & 7) * 128;

    if (isQ) {
        u32 bk = 0;
#pragma unroll 1
        for (int t = 0; t < CW; ++t) {
            const int bi = t & 1;
            const bf16*  eb_i = bi ? p.e_b1 : p.e_b0;
            const float* ef_i = bi ? p.e_f1 : p.e_f0;
            bf16*  eb_o = bi ? p.e_b0 : p.e_b1;
            float* ef_o = bi ? p.e_f0 : p.e_f1;

            // Q1: GRU encoder
            stage_act(abuf, tid, r0, p.x_b + (long)t * CIN, (long)CW * CIN, CIN, true,
                      eb_i, CH);
            gru_compute(abuf, r0, n0, lane, wave, p.Wih_qb, p.Whh_qb,
                        p.bih_q, p.bhh_q, ef_i, ef_o, eb_o);
            gbar_h(p.barQ, wgl, ++bk);
            // Q2: d = [zflow[t] | e(t)] @ Wd_q^T
            stage_act(abuf, tid, r0, p.zflow + (size_t)bi * CB * CZ, CZ, CZ, false,
                      eb_o, CH);
            lin_compute(abuf, r0, n0, lane, wave, CZ + CH, p.Wd_qb, p.bd_q, p.dvec_b);
            gbar_h(p.barQ, wgl, ++bk);
            // Q3: mu / lv / reparam z
            phase_tail2<0>(p, t, wgl, tid, lane, wave, Ra, Rs,
                           p.dvec_b, p.Wmu_qb, p.Wsg_qb, p.bmu_q, p.bsig_q);
            gbar_h(p.barQ, wgl, ++bk);
            // Q4: flows + LGSSM
            phase_flows2(p, wgl, tid, t, ZLp, PSp);
            asm volatile("s_waitcnt vmcnt(0)" ::: "memory");
            __syncthreads();
            if (tid == 0)
                __hip_atomic_store(&p.zbar[wgl], (u32)(t + 1),
                                   __ATOMIC_RELAXED, __HIP_MEMORY_SCOPE_AGENT);
            __syncthreads();
        }
    } else {
        u32 bk = 0;
#pragma unroll 1
        for (int t = 0; t < CW; ++t) {
            if (tid < 128) {
                while (__hip_atomic_load(&p.zbar[tid], __ATOMIC_RELAXED,
                                         __HIP_MEMORY_SCOPE_AGENT) < (u32)(t + 1))
                    __builtin_amdgcn_s_sleep(2);
            }
            __syncthreads();

            const int bi = t & 1;
            const bf16*  db_i = bi ? p.d_b1 : p.d_b0;
            const float* df_i = bi ? p.d_f1 : p.d_f0;
            bf16*  db_o = bi ? p.d_b0 : p.d_b1;
            float* df_o = bi ? p.d_f0 : p.d_f1;

            // P1: GRU decoder
            stage_act(abuf, tid, r0, p.ztlg + (size_t)bi * CB * CZ, CZ, CZ, false,
                      db_i, CH);
            gru_compute(abuf, r0, n0, lane, wave, p.Wih_pb, p.Whh_pb,
                        p.bih_p, p.bhh_p, df_i, df_o, db_o);
            gbar_h(p.barP, wgl, ++bk);
            // P2: dd = d(t) @ Wd_p^T
            stage_act(abuf, tid, r0, nullptr, 0, 0, false, db_o, CH);
            lin_compute(abuf, r0, n0, lane, wave, CH, p.Wd_pb, p.bd_p, p.ddvec_b);
            gbar_h(p.barP, wgl, ++bk);
            // P3: output head
            phase_tail2<1>(p, t, wgl, tid, lane, wave, Ra, Rs,
                           p.ddvec_b, p.Wmu_pb, p.Wsg_pb, p.bmu_p, p.bsig_p);
        }
    }
}

// ---------------------------------------------------------------------------
// Host driver
// ---------------------------------------------------------------------------
extern "C" void kernel_launch(void* const* d_in, const int* in_sizes, int n_in,
                              void* d_out, int out_size, void* d_ws, size_t ws_size,
                              hipStream_t stream)
{
    Prm p;
    const float* x      = (const float*)d_in[0];
    p.eps_q  = (const float*)d_in[1];
    p.eps_p  = (const float*)d_in[2];
    const float* Wih_q  = (const float*)d_in[3];
    const float* Whh_q  = (const float*)d_in[4];
    p.bih_q  = (const float*)d_in[5];
    p.bhh_q  = (const float*)d_in[6];
    const float* Wd_q   = (const float*)d_in[7];
    p.bd_q   = (const float*)d_in[8];
    const float* Wmu_q  = (const float*)d_in[9];
    p.bmu_q  = (const float*)d_in[10];
    const float* Wsig_q = (const float*)d_in[11];
    p.bsig_q = (const float*)d_in[12];
    p.Wp     = (const float*)d_in[13];
    p.bp     = (const float*)d_in[14];
    p.up     = (const float*)d_in[15];
    p.Wlg    = (const float*)d_in[16];
    p.blg    = (const float*)d_in[17];
    const float* Wih_p  = (const float*)d_in[18];
    const float* Whh_p  = (const float*)d_in[19];
    p.bih_p  = (const float*)d_in[20];
    p.bhh_p  = (const float*)d_in[21];
    const float* Wd_p   = (const float*)d_in[22];
    p.bd_p   = (const float*)d_in[23];
    const float* Wmu_p  = (const float*)d_in[24];
    p.bmu_p  = (const float*)d_in[25];
    const float* Wsig_p = (const float*)d_in[26];
    p.bsig_p = (const float*)d_in[27];

    p.out_o  = (float*)d_out;
    p.out_mu = p.out_o + (size_t)CB * CW * COUT;
    p.out_lv = p.out_mu + (size_t)CB * CW * CZ;

    char* wp_ = (char*)d_ws;
    auto carve = [&](size_t bytes) -> void* {
        void* q = (void*)wp_;
        wp_ += (bytes + 255) & ~(size_t)255;
        return q;
    };
    p.e_f0 = (float*)carve((size_t)CB * CH * 4);
    p.e_f1 = (float*)carve((size_t)CB * CH * 4);
    p.d_f0 = (float*)carve((size_t)CB * CH * 4);
    p.d_f1 = (float*)carve((size_t)CB * CH * 4);
    p.e_b0 = (bf16*)carve((size_t)CB * CH * 2);
    p.e_b1 = (bf16*)carve((size_t)CB * CH * 2);
    p.d_b0 = (bf16*)carve((size_t)CB * CH * 2);
    p.d_b1 = (bf16*)carve((size_t)CB * CH * 2);
    p.ztmp_f  = (float*)carve((size_t)CB * CZ * 4);
    p.dvec_b  = (bf16*)carve((size_t)CB * CD * 2);
    p.ddvec_b = (bf16*)carve((size_t)CB * CD * 2);
    p.zflow   = (bf16*)carve((size_t)2 * CB * CZ * 2);
    p.ztlg    = (bf16*)carve((size_t)2 * CB * CZ * 2);
    p.barQ    = (u32*)carve(512);
    p.barP    = (u32*)carve(512);
    p.zbar    = (u32*)carve(512);
    bf16* x_b    = (bf16*)carve((size_t)CB * CW * CIN * 2);
    bf16* Wih_qb = (bf16*)carve((size_t)3 * CH * CIN * 2);
    bf16* Whh_qb = (bf16*)carve((size_t)3 * CH * CH * 2);
    bf16* Wd_qb  = (bf16*)carve((size_t)CD * (CZ + CH) * 2);
    bf16* Wmu_qb = (bf16*)carve((size_t)CZ * CD * 2);
    bf16* Wsg_qb = (bf16*)carve((size_t)CZ * CD * 2);
    bf16* Wih_pb = (bf16*)carve((size_t)3 * CH * CZ * 2);
    bf16* Whh_pb = (bf16*)carve((size_t)3 * CH * CH * 2);
    bf16* Wd_pb  = (bf16*)carve((size_t)CD * CH * 2);
    bf16* Wmu_pb = (bf16*)carve((size_t)COUT * CD * 2);
    bf16* Wsg_pb = (bf16*)carve((size_t)COUT * CD * 2);
    p.x_b = x_b;       p.Wih_qb = Wih_qb; p.Whh_qb = Whh_qb;
    p.Wd_qb = Wd_qb;   p.Wmu_qb = Wmu_qb; p.Wsg_qb = Wsg_qb;
    p.Wih_pb = Wih_pb; p.Whh_pb = Whh_pb; p.Wd_pb = Wd_pb;
    p.Wmu_pb = Wmu_pb; p.Wsg_pb = Wsg_pb;

    hipMemsetAsync(p.e_f0, 0, (size_t)CB * CH * 4, stream);
    hipMemsetAsync(p.d_f0, 0, (size_t)CB * CH * 4, stream);
    hipMemsetAsync(p.e_b0, 0, (size_t)CB * CH * 2, stream);
    hipMemsetAsync(p.d_b0, 0, (size_t)CB * CH * 2, stream);
    hipMemsetAsync(p.zflow, 0, (size_t)CB * CZ * 2, stream);   // slot 0 = zeros
    hipMemsetAsync(p.barQ, 0, 512, stream);
    hipMemsetAsync(p.barP, 0, 512, stream);
    hipMemsetAsync(p.zbar, 0, 512, stream);

    auto cvt = [&](const float* s, bf16* d, size_t n) {
        k_cvt<<<dim3((unsigned)((n / 4 + 255) / 256)), dim3(256), 0, stream>>>(s, d, (int)n);
    };
    cvt(x,      x_b,    (size_t)CB * CW * CIN);
    cvt(Wih_q,  Wih_qb, (size_t)3 * CH * CIN);
    cvt(Whh_q,  Whh_qb, (size_t)3 * CH * CH);
    cvt(Wd_q,   Wd_qb,  (size_t)CD * (CZ + CH));
    cvt(Wmu_q,  Wmu_qb, (size_t)CZ * CD);
    cvt(Wsig_q, Wsg_qb, (size_t)CZ * CD);
    cvt(Wih_p,  Wih_pb, (size_t)3 * CH * CZ);
    cvt(Whh_p,  Whh_pb, (size_t)3 * CH * CH);
    cvt(Wd_p,   Wd_pb,  (size_t)CD * CH);
    cvt(Wmu_p,  Wmu_pb, (size_t)COUT * CD);
    cvt(Wsig_p, Wsg_pb, (size_t)COUT * CD);

    mega<<<dim3(256), dim3(512), SMEM_BYTES, stream>>>(p);
}

// Round 14
// 8980.781 us; speedup vs baseline: 2.6699x; 1.1532x over previous
//
#include <hip/hip_runtime.h>

// ---------------------------------------------------------------------------
// OmniAnomaly forward, round 14: XCD-local slab groups.
// gid = wg&7 (nominal XCD, round-robin assumption). XCD gid's 32 WGs:
//   m=wg>>3: m 0-7 -> Q slab 2gid, 8-15 -> Q slab 2gid+1,
//            m 16-23 -> P slab 2gid, 24-31 -> P slab 2gid+1 (8 col-slices each).
// Entire Q and P chains for a slab are computed within ONE XCD -> state
// exchange via sc0-only loads/stores through that XCD's L2; barriers are
// 8-WG group flags. Runtime check via HW_REG_XCC_ID: if any nominal group
// straddles XCDs, fall back to sc0sc1 device-coherent path (r13-proven).
// Flags always agent-scope atomics (hang-safe regardless of placement).
// B=256, W=128, IN=128, H=1024, Z=128, D=1024, OUT=128, K=3 flows
// ---------------------------------------------------------------------------

typedef __bf16 bf16;
typedef __bf16 bf16x8 __attribute__((ext_vector_type(8)));
typedef float  f32x4  __attribute__((ext_vector_type(4)));
typedef unsigned u32;

static constexpr int CB   = 256;
static constexpr int CW   = 128;
static constexpr int CIN  = 128;
static constexpr int CH   = 1024;
static constexpr int CZ   = 128;
static constexpr int CD   = 1024;
static constexpr int COUT = 128;

static constexpr int APITCH     = 1160;                      // 1152 + 8 pad
static constexpr int ABUF_BYTES = 16 * APITCH * 2;           // 37120
static constexpr int REDN       = 8 * 16 * 17;
static constexpr int RED2_BYTES = 2 * REDN * 4;              // 17408
static constexpr int FLOW_BYTES = (2 * CZ + 2 * 2 * CZ) * 4; // 3072
static constexpr int SMEM_BYTES = ABUF_BYTES + RED2_BYTES + FLOW_BYTES; // 57600

// s_getreg imm: ID=20 (HW_REG_XCC_ID), offset 0, width 32 -> 20 | (31<<11)
static constexpr int XCC_GETREG = 20 | (31 << 11);

#define DEV static __device__ __forceinline__

DEV float sigmoidf_(float x) { return 1.0f / (1.0f + expf(-x)); }
DEV float softplusf_(float x) { return x > 20.0f ? x : log1pf(expf(x)); }
DEV bf16x8 ldfrag(const bf16* p) { return *reinterpret_cast<const bf16x8*>(p); }

#define MFMA(a, b, c) __builtin_amdgcn_mfma_f32_16x16x32_bf16((a), (b), (c), 0, 0, 0)

// ---- mode-dependent coherent accesses ----
// FAST: producers/consumers share one XCD-L2 -> sc0 only (L1 bypass, L2 hit).
// SLOW: device scope -> sc0 sc1 (r13-proven).
template <bool FAST> DEV bf16x8 ldx16(const bf16* p) {
    bf16x8 v;
    if constexpr (FAST)
        asm volatile("global_load_dwordx4 %0, %1, off sc0\n\ts_waitcnt vmcnt(0)"
                     : "=v"(v) : "v"(p) : "memory");
    else
        asm volatile("global_load_dwordx4 %0, %1, off sc0 sc1\n\ts_waitcnt vmcnt(0)"
                     : "=v"(v) : "v"(p) : "memory");
    return v;
}
template <bool FAST> DEV u32 ldx4(const void* p) {
    u32 v;
    if constexpr (FAST)
        asm volatile("global_load_dword %0, %1, off sc0\n\ts_waitcnt vmcnt(0)"
                     : "=v"(v) : "v"(p) : "memory");
    else
        asm volatile("global_load_dword %0, %1, off sc0 sc1\n\ts_waitcnt vmcnt(0)"
                     : "=v"(v) : "v"(p) : "memory");
    return v;
}
template <bool FAST> DEV void stx4(void* p, u32 v) {
    if constexpr (FAST)
        asm volatile("global_store_dword %0, %1, off sc0" :: "v"(p), "v"(v) : "memory");
    else
        asm volatile("global_store_dword %0, %1, off sc0 sc1" :: "v"(p), "v"(v) : "memory");
}
DEV u32 pk2(float a, float b) {
    union { bf16 h[2]; u32 u; } r;
    r.h[0] = (bf16)a; r.h[1] = (bf16)b;
    return r.u;
}

struct Prm {
    const float *eps_q, *eps_p;
    const float *bih_q, *bhh_q, *bd_q, *bmu_q, *bsig_q;
    const float *Wp, *bp, *up, *Wlg, *blg;
    const float *bih_p, *bhh_p, *bd_p, *bmu_p, *bsig_p;
    const bf16 *x_b, *Wih_qb, *Whh_qb, *Wd_qb, *Wmu_qb, *Wsg_qb;
    const bf16 *Wih_pb, *Whh_pb, *Wd_pb, *Wmu_pb, *Wsg_pb;
    float *e_f0, *e_f1, *d_f0, *d_f1;   // fp32 masters (WG-private cols, cached)
    bf16 *e_b0, *e_b1, *d_b0, *d_b1;    // bf16 shadows (group-shared)
    float *ztmp_f;
    bf16 *dvec_b, *ddvec_b;
    bf16 *zflow;    // [2][CB][CZ]
    bf16 *ztlg;     // [2][CB][CZ]
    u32 *qbar, *pbar;       // [16 slabs][8 slices] * 16-u32 spacing
    u32 *zbar, *pdone;      // [16 slabs] * 16-u32 spacing
    u32 *xcc, *cnt;         // startup
    float *out_o, *out_mu, *out_lv;
};

// 8-WG group barrier (flags agent-scope -> correct on any placement).
DEV void gbar_g(u32* flg, int slice, u32 k)
{
    asm volatile("s_waitcnt vmcnt(0)" ::: "memory");
    __syncthreads();
    if (threadIdx.x == 0)
        __hip_atomic_store(&flg[slice * 16], k, __ATOMIC_RELAXED, __HIP_MEMORY_SCOPE_AGENT);
    if (threadIdx.x < 8) {
        while (__hip_atomic_load(&flg[threadIdx.x * 16], __ATOMIC_RELAXED,
                                 __HIP_MEMORY_SCOPE_AGENT) < k)
            __builtin_amdgcn_s_sleep(1);
    }
    __syncthreads();
}

// ---------------------------------------------------------------------------
__global__ void k_cvt(const float* __restrict__ src, bf16* __restrict__ dst, int n)
{
    int i = (blockIdx.x * blockDim.x + threadIdx.x) * 4;
    if (i < n) {
        float4 v = *reinterpret_cast<const float4*>(src + i);
        *reinterpret_cast<u32*>(dst + i)     = pk2(v.x, v.y);
        *reinterpret_cast<u32*>(dst + i + 2) = pk2(v.z, v.w);
    }
}

// ---------------------------------------------------------------------------
// Stage slab rows [r0,+16) x [head(K1) | body(CH)] into abuf.
// ---------------------------------------------------------------------------
template <bool FAST, bool HC>
DEV void stage_act(bf16* abuf, int tid, int r0,
                   const bf16* head, long hs, int K1,
                   const bf16* body, long bs)
{
    const int CHN = (K1 + CH) >> 3;
    const int TOT = 16 * CHN;
    for (int idx = tid; idx < TOT; idx += 512) {
        const int row = idx / CHN;
        const int k = (idx - row * CHN) * 8;
        bf16x8 v;
        if (k < K1) {
            const bf16* s = head + (long)(r0 + row) * hs + k;
            v = HC ? ldfrag(s) : ldx16<FAST>(s);
        } else {
            v = ldx16<FAST>(body + (long)(r0 + row) * bs + (k - K1));
        }
        *reinterpret_cast<bf16x8*>(abuf + (long)row * APITCH + k) = v;
    }
    __syncthreads();
}

// ---------------------------------------------------------------------------
// GRU compute (r13 verbatim; mode stores for the bf16 shadow).
// ---------------------------------------------------------------------------
template <bool FAST>
DEV void gru_compute(const bf16* abuf, int r0, int n0, int lane, int wave,
                     const bf16* __restrict__ Wih, const bf16* __restrict__ Whh,
                     const float* __restrict__ bih, const float* __restrict__ bhh,
                     const float* __restrict__ Efin,
                     float* __restrict__ Efo, bf16* __restrict__ Ebo)
{
    const int lr = lane & 15, lkE = (lane >> 4) * 8;
    const int c = n0 + wave * 16 + lr;
    const bf16* arow = abuf + (long)lr * APITCH;

    f32x4 acc[4] = {};
#pragma unroll 4
    for (int k = 0; k < CIN; k += 32) {
        bf16x8 a = *reinterpret_cast<const bf16x8*>(arow + k + lkE);
#pragma unroll
        for (int g = 0; g < 3; ++g) {
            bf16x8 b = ldfrag(Wih + ((long)g * CH + c) * CIN + k + lkE);
            const int grp = (g == 2) ? 2 : g;
            acc[grp] = MFMA(a, b, acc[grp]);
        }
    }
#pragma unroll 4
    for (int k = 0; k < CH; k += 32) {
        bf16x8 a = *reinterpret_cast<const bf16x8*>(arow + CIN + k + lkE);
#pragma unroll
        for (int g = 0; g < 3; ++g) {
            bf16x8 b = ldfrag(Whh + ((long)g * CH + c) * CH + k + lkE);
            const int grp = (g == 2) ? 3 : g;
            acc[grp] = MFMA(a, b, acc[grp]);
        }
    }

    const float b0r = bih[c] + bhh[c];
    const float b0z = bih[CH + c] + bhh[CH + c];
    const float bin = bih[2 * CH + c];
    const float bhn = bhh[2 * CH + c];
    const int rbase = r0 + (lane >> 4) * 4;
#pragma unroll
    for (int i = 0; i < 4; ++i) {
        const int row = rbase + i;
        float r = sigmoidf_(acc[0][i] + b0r);
        float u = sigmoidf_(acc[1][i] + b0z);
        float n = tanhf(acc[2][i] + bin + r * (acc[3][i] + bhn));
        float en = (1.0f - u) * n + u * Efin[(long)row * CH + c];
        Efo[(long)row * CH + c] = en;
        float vB = __shfl_xor(en, 1);
        if (!(lane & 1))
            stx4<FAST>(Ebo + (long)row * CH + c, pk2(en, vB));
    }
}

// ---------------------------------------------------------------------------
template <bool FAST>
DEV void lin_compute(const bf16* abuf, int r0, int n0, int lane, int wave, int Ktot,
                     const bf16* __restrict__ W,
                     const float* __restrict__ bias, bf16* __restrict__ Out)
{
    const int lr = lane & 15, lkE = (lane >> 4) * 8;
    const int c = n0 + wave * 16 + lr;
    const bf16* arow = abuf + (long)lr * APITCH;
    const bf16* wrow = W + (long)c * Ktot;

    f32x4 acc = {};
#pragma unroll 4
    for (int k = 0; k < CH; k += 32) {
        bf16x8 a = *reinterpret_cast<const bf16x8*>(arow + (Ktot - CH) + k + lkE);
        bf16x8 b = ldfrag(wrow + (Ktot - CH) + k + lkE);
        acc = MFMA(a, b, acc);
    }
    if (Ktot > CH) {
#pragma unroll 4
        for (int k = 0; k < CZ; k += 32) {
            bf16x8 a = *reinterpret_cast<const bf16x8*>(arow + k + lkE);
            bf16x8 b = ldfrag(wrow + k + lkE);
            acc = MFMA(a, b, acc);
        }
    }

    const float bb = bias[c];
    const int rbase = r0 + (lane >> 4) * 4;
#pragma unroll
    for (int i = 0; i < 4; ++i) {
        float v = acc[i] + bb;
        float vB = __shfl_xor(v, 1);
        if (!(lane & 1))
            stx4<FAST>(Out + (long)(rbase + i) * CD + c, pk2(v, vB));
    }
}

// ---------------------------------------------------------------------------
// Two-head tail: WG covers rows slab*16..+16 x cols slice*16..+16, 8-wave
// K-split over K=1024 with LDS reduce.
// ---------------------------------------------------------------------------
template <bool FAST, int MODE>
DEV void phase_tail2(const Prm& p, int t, int slab, int slice, int tid,
                     int lane, int wave, float* Ra, float* Rs,
                     const bf16* __restrict__ A,
                     const bf16* __restrict__ Wa, const bf16* __restrict__ Wb,
                     const float* __restrict__ ba, const float* __restrict__ bb)
{
    const int lr = lane & 15, lkE = (lane >> 4) * 8;
    const int mb = slab * 16;
    const int nb = slice * 16;
    f32x4 am = {}, as = {};
    const int k0 = wave * 128;
#pragma unroll
    for (int kk = 0; kk < 128; kk += 32) {
        const int k = k0 + kk;
        bf16x8 a  = ldx16<FAST>(A + (long)(mb + lr) * CD + k + lkE);
        bf16x8 bm = ldfrag(Wa + (long)(nb + lr) * CD + k + lkE);
        bf16x8 bs = ldfrag(Wb + (long)(nb + lr) * CD + k + lkE);
        am = MFMA(a, bm, am);
        as = MFMA(a, bs, as);
    }
    __syncthreads();
#pragma unroll
    for (int i = 0; i < 4; ++i) {
        Ra[(wave * 16 + (lane >> 4) * 4 + i) * 17 + lr] = am[i];
        Rs[(wave * 16 + (lane >> 4) * 4 + i) * 17 + lr] = as[i];
    }
    __syncthreads();
    if (tid < 256) {
        const int trow = tid >> 4, tcol = tid & 15;
        float vm = 0.f, vs = 0.f;
#pragma unroll
        for (int w = 0; w < 8; ++w) {
            vm += Ra[(w * 16 + trow) * 17 + tcol];
            vs += Rs[(w * 16 + trow) * 17 + tcol];
        }
        const int row = mb + trow, col = nb + tcol;
        if constexpr (MODE == 0) {
            float mu = vm + ba[col];
            float lv = softplusf_(vs + bb[col]);
            float e  = p.eps_q[(long)row * CW * CZ + (long)t * CZ + col];
            float z  = mu + expf(0.5f * lv) * e;
            p.out_mu[(long)row * CW * CZ + (long)t * CZ + col] = mu;
            p.out_lv[(long)row * CW * CZ + (long)t * CZ + col] = lv;
            stx4<FAST>(p.ztmp_f + (long)row * CZ + col, __float_as_uint(z));
        } else {
            float m  = vm + ba[col];
            float sg = softplusf_(vs + bb[col]);
            float e  = p.eps_p[(long)row * CW * COUT + (long)t * COUT + col];
            p.out_o[(long)row * CW * COUT + (long)t * COUT + col] = m + sg * e;
        }
    }
}

// ---------------------------------------------------------------------------
// Planar flows + LGSSM: 2 rows/WG (rows = slab*16 + slice*2 + rg).
// ---------------------------------------------------------------------------
template <bool FAST>
DEV void phase_flows2(const Prm& p, int rowbase, int tid, int t, float* zl, float* ps)
{
    const int rg = tid >> 8;
    const int sub = tid & 255;
    const int c = sub & 127, half = sub >> 7;
    const int row = rowbase + rg;
    float* zrow = zl + rg * CZ;
    float* pall = ps + rg * 2 * CZ;

    if (half == 0)
        zrow[c] = __uint_as_float(ldx4<FAST>(p.ztmp_f + (long)row * CZ + c));
    __syncthreads();

#pragma unroll 1
    for (int kf = 0; kf < 3; ++kf) {
        const float* wr = p.Wp + ((long)kf * CZ + c) * CZ + half * 64;
        const float* zh = zrow + half * 64;
        float s = 0.f;
#pragma unroll
        for (int j = 0; j < 64; j += 4) {
            float4 w = *reinterpret_cast<const float4*>(wr + j);
            s += zh[j] * w.x + zh[j + 1] * w.y + zh[j + 2] * w.z + zh[j + 3] * w.w;
        }
        pall[half * CZ + c] = s;
        __syncthreads();
        if (half == 0) {
            float sf = pall[c] + pall[CZ + c] + p.bp[kf * CZ + c];
            zrow[c] += p.up[kf] * tanhf(sf);
        }
        __syncthreads();
    }
    {
        const float* wr = p.Wlg + (long)c * CZ + half * 64;
        const float* zh = zrow + half * 64;
        float s = 0.f;
#pragma unroll
        for (int j = 0; j < 64; j += 4) {
            float4 w = *reinterpret_cast<const float4*>(wr + j);
            s += zh[j] * w.x + zh[j + 1] * w.y + zh[j + 2] * w.z + zh[j + 3] * w.w;
        }
        pall[half * CZ + c] = s;
        __syncthreads();
        if (half == 0) {
            float zt = pall[c] + pall[CZ + c] + p.blg[c];
            float ztB = __shfl_xor(zt, 1);
            if (!(c & 1)) {
                stx4<FAST>(p.ztlg + ((size_t)(t & 1) * CB + row) * CZ + c, pk2(zt, ztB));
                stx4<FAST>(p.zflow + ((size_t)((t + 1) & 1) * CB + row) * CZ + c,
                           pk2(zrow[c], zrow[c + 1]));
            }
        }
    }
}

// ---------------------------------------------------------------------------
// Q / P role loops.
// ---------------------------------------------------------------------------
template <bool FAST>
DEV void run_q(const Prm& p, int slab, int slice, int tid,
               bf16* abuf, float* Ra, float* Rs, float* ZLp, float* PSp)
{
    const int lane = tid & 63, wave = tid >> 6;
    const int r0 = slab * 16, n0 = slice * 128;
    u32* qb = p.qbar + slab * 8 * 16;
    u32 bk = 0;
#pragma unroll 1
    for (int t = 0; t < CW; ++t) {
        const int bi = t & 1;
        const bf16*  eb_i = bi ? p.e_b1 : p.e_b0;
        const float* ef_i = bi ? p.e_f1 : p.e_f0;
        bf16*  eb_o = bi ? p.e_b0 : p.e_b1;
        float* ef_o = bi ? p.e_f0 : p.e_f1;

        // Q1: GRU encoder
        stage_act<FAST, true>(abuf, tid, r0, p.x_b + (long)t * CIN, (long)CW * CIN,
                              CIN, eb_i, CH);
        gru_compute<FAST>(abuf, r0, n0, lane, wave, p.Wih_qb, p.Whh_qb,
                          p.bih_q, p.bhh_q, ef_i, ef_o, eb_o);
        gbar_g(qb, slice, ++bk);
        // Q2: d = [zflow[t] | e(t)] @ Wd_q^T
        stage_act<FAST, false>(abuf, tid, r0, p.zflow + (size_t)bi * CB * CZ,
                               CZ, CZ, eb_o, CH);
        lin_compute<FAST>(abuf, r0, n0, lane, wave, CZ + CH, p.Wd_qb, p.bd_q, p.dvec_b);
        gbar_g(qb, slice, ++bk);
        // Q3: mu / lv / reparam z
        phase_tail2<FAST, 0>(p, t, slab, slice, tid, lane, wave, Ra, Rs,
                             p.dvec_b, p.Wmu_qb, p.Wsg_qb, p.bmu_q, p.bsig_q);
        gbar_g(qb, slice, ++bk);
        // Q4: back-pressure (ztlg slot reuse), then flows + LGSSM
        if (t >= 2) {
            if (tid == 0) {
                while ((int)__hip_atomic_load(&p.pdone[slab * 16], __ATOMIC_RELAXED,
                                              __HIP_MEMORY_SCOPE_AGENT) < t - 1)
                    __builtin_amdgcn_s_sleep(2);
            }
            __syncthreads();
        }
        phase_flows2<FAST>(p, slab * 16 + slice * 2, tid, t, ZLp, PSp);
        gbar_g(qb, slice, ++bk);
        if (slice == 0 && tid == 0)
            __hip_atomic_store(&p.zbar[slab * 16], (u32)(t + 1),
                               __ATOMIC_RELAXED, __HIP_MEMORY_SCOPE_AGENT);
    }
}

template <bool FAST>
DEV void run_p(const Prm& p, int slab, int slice, int tid,
               bf16* abuf, float* Ra, float* Rs)
{
    const int lane = tid & 63, wave = tid >> 6;
    const int r0 = slab * 16, n0 = slice * 128;
    u32* pb = p.pbar + slab * 8 * 16;
    u32 bk = 0;
#pragma unroll 1
    for (int t = 0; t < CW; ++t) {
        if (tid == 0) {
            while (__hip_atomic_load(&p.zbar[slab * 16], __ATOMIC_RELAXED,
                                     __HIP_MEMORY_SCOPE_AGENT) < (u32)(t + 1))
                __builtin_amdgcn_s_sleep(2);
        }
        __syncthreads();

        const int bi = t & 1;
        const bf16*  db_i = bi ? p.d_b1 : p.d_b0;
        const float* df_i = bi ? p.d_f1 : p.d_f0;
        bf16*  db_o = bi ? p.d_b0 : p.d_b1;
        float* df_o = bi ? p.d_f0 : p.d_f1;

        // P1: GRU decoder
        stage_act<FAST, false>(abuf, tid, r0, p.ztlg + (size_t)bi * CB * CZ,
                               CZ, CZ, db_i, CH);
        gru_compute<FAST>(abuf, r0, n0, lane, wave, p.Wih_pb, p.Whh_pb,
                          p.bih_p, p.bhh_p, df_i, df_o, db_o);
        gbar_g(pb, slice, ++bk);
        if (slice == 0 && tid == 0)
            __hip_atomic_store(&p.pdone[slab * 16], (u32)(t + 1),
                               __ATOMIC_RELAXED, __HIP_MEMORY_SCOPE_AGENT);
        // P2: dd = d(t) @ Wd_p^T
        stage_act<FAST, false>(abuf, tid, r0, nullptr, 0, 0, db_o, CH);
        lin_compute<FAST>(abuf, r0, n0, lane, wave, CH, p.Wd_pb, p.bd_p, p.ddvec_b);
        gbar_g(pb, slice, ++bk);
        // P3: output head (ddvec reuse protected by next P1 gbar)
        phase_tail2<FAST, 1>(p, t, slab, slice, tid, lane, wave, Ra, Rs,
                             p.ddvec_b, p.Wmu_pb, p.Wsg_pb, p.bmu_p, p.bsig_p);
    }
}

// ---------------------------------------------------------------------------
__launch_bounds__(512)
__global__ void mega(Prm p)
{
    extern __shared__ char smem[];
    bf16*  abuf = (bf16*)smem;
    float* Ra   = (float*)(smem + ABUF_BYTES);
    float* Rs   = Ra + REDN;
    float* ZLp  = (float*)(smem + ABUF_BYTES + RED2_BYTES);
    float* PSp  = ZLp + 2 * CZ;
    __shared__ int s_fast;

    const int wg = blockIdx.x, tid = threadIdx.x;
    const int gid = wg & 7, m = wg >> 3;
    const bool isQ = m < 16;
    const int slab = gid * 2 + ((m & 15) >> 3);
    const int slice = m & 7;

    // ---- startup: publish physical XCD id, verify nominal groups ----
    const u32 myx = (u32)__builtin_amdgcn_s_getreg(XCC_GETREG);
    if (tid == 0) {
        __hip_atomic_store(&p.xcc[wg * 16], myx, __ATOMIC_RELAXED, __HIP_MEMORY_SCOPE_AGENT);
        __hip_atomic_fetch_add(p.cnt, 1u, __ATOMIC_RELAXED, __HIP_MEMORY_SCOPE_AGENT);
        while (__hip_atomic_load(p.cnt, __ATOMIC_RELAXED, __HIP_MEMORY_SCOPE_AGENT) < 256u)
            __builtin_amdgcn_s_sleep(2);
    }
    __syncthreads();
    if (tid < 64) {
        bool eq = true;
        if (tid < 32) {
            u32 o = __hip_atomic_load(&p.xcc[(gid + 8 * tid) * 16],
                                      __ATOMIC_RELAXED, __HIP_MEMORY_SCOPE_AGENT);
            eq = (o == myx);
        }
        unsigned long long b = __ballot(eq);
        if (tid == 0) s_fast = (b == ~0ull) ? 1 : 0;
    }
    __syncthreads();
    const bool fast = (s_fast != 0);

    if (isQ) {
        if (fast) run_q<true>(p, slab, slice, tid, abuf, Ra, Rs, ZLp, PSp);
        else      run_q<false>(p, slab, slice, tid, abuf, Ra, Rs, ZLp, PSp);
    } else {
        if (fast) run_p<true>(p, slab, slice, tid, abuf, Ra, Rs);
        else      run_p<false>(p, slab, slice, tid, abuf, Ra, Rs);
    }
}

// ---------------------------------------------------------------------------
// Host driver
// ---------------------------------------------------------------------------
extern "C" void kernel_launch(void* const* d_in, const int* in_sizes, int n_in,
                              void* d_out, int out_size, void* d_ws, size_t ws_size,
                              hipStream_t stream)
{
    Prm p;
    const float* x      = (const float*)d_in[0];
    p.eps_q  = (const float*)d_in[1];
    p.eps_p  = (const float*)d_in[2];
    const float* Wih_q  = (const float*)d_in[3];
    const float* Whh_q  = (const float*)d_in[4];
    p.bih_q  = (const float*)d_in[5];
    p.bhh_q  = (const float*)d_in[6];
    const float* Wd_q   = (const float*)d_in[7];
    p.bd_q   = (const float*)d_in[8];
    const float* Wmu_q  = (const float*)d_in[9];
    p.bmu_q  = (const float*)d_in[10];
    const float* Wsig_q = (const float*)d_in[11];
    p.bsig_q = (const float*)d_in[12];
    p.Wp     = (const float*)d_in[13];
    p.bp     = (const float*)d_in[14];
    p.up     = (const float*)d_in[15];
    p.Wlg    = (const float*)d_in[16];
    p.blg    = (const float*)d_in[17];
    const float* Wih_p  = (const float*)d_in[18];
    const float* Whh_p  = (const float*)d_in[19];
    p.bih_p  = (const float*)d_in[20];
    p.bhh_p  = (const float*)d_in[21];
    const float* Wd_p   = (const float*)d_in[22];
    p.bd_p   = (const float*)d_in[23];
    const float* Wmu_p  = (const float*)d_in[24];
    p.bmu_p  = (const float*)d_in[25];
    const float* Wsig_p = (const float*)d_in[26];
    p.bsig_p = (const float*)d_in[27];

    p.out_o  = (float*)d_out;
    p.out_mu = p.out_o + (size_t)CB * CW * COUT;
    p.out_lv = p.out_mu + (size_t)CB * CW * CZ;

    char* wp_ = (char*)d_ws;
    auto carve = [&](size_t bytes) -> void* {
        void* q = (void*)wp_;
        wp_ += (bytes + 255) & ~(size_t)255;
        return q;
    };
    p.e_f0 = (float*)carve((size_t)CB * CH * 4);
    p.e_f1 = (float*)carve((size_t)CB * CH * 4);
    p.d_f0 = (float*)carve((size_t)CB * CH * 4);
    p.d_f1 = (float*)carve((size_t)CB * CH * 4);
    p.e_b0 = (bf16*)carve((size_t)CB * CH * 2);
    p.e_b1 = (bf16*)carve((size_t)CB * CH * 2);
    p.d_b0 = (bf16*)carve((size_t)CB * CH * 2);
    p.d_b1 = (bf16*)carve((size_t)CB * CH * 2);
    p.ztmp_f  = (float*)carve((size_t)CB * CZ * 4);
    p.dvec_b  = (bf16*)carve((size_t)CB * CD * 2);
    p.ddvec_b = (bf16*)carve((size_t)CB * CD * 2);
    p.zflow   = (bf16*)carve((size_t)2 * CB * CZ * 2);
    p.ztlg    = (bf16*)carve((size_t)2 * CB * CZ * 2);
    p.qbar    = (u32*)carve((size_t)16 * 8 * 16 * 4);
    p.pbar    = (u32*)carve((size_t)16 * 8 * 16 * 4);
    p.zbar    = (u32*)carve((size_t)16 * 16 * 4);
    p.pdone   = (u32*)carve((size_t)16 * 16 * 4);
    p.xcc     = (u32*)carve((size_t)256 * 16 * 4);
    p.cnt     = (u32*)carve(256);
    bf16* x_b    = (bf16*)carve((size_t)CB * CW * CIN * 2);
    bf16* Wih_qb = (bf16*)carve((size_t)3 * CH * CIN * 2);
    bf16* Whh_qb = (bf16*)carve((size_t)3 * CH * CH * 2);
    bf16* Wd_qb  = (bf16*)carve((size_t)CD * (CZ + CH) * 2);
    bf16* Wmu_qb = (bf16*)carve((size_t)CZ * CD * 2);
    bf16* Wsg_qb = (bf16*)carve((size_t)CZ * CD * 2);
    bf16* Wih_pb = (bf16*)carve((size_t)3 * CH * CZ * 2);
    bf16* Whh_pb = (bf16*)carve((size_t)3 * CH * CH * 2);
    bf16* Wd_pb  = (bf16*)carve((size_t)CD * CH * 2);
    bf16* Wmu_pb = (bf16*)carve((size_t)COUT * CD * 2);
    bf16* Wsg_pb = (bf16*)carve((size_t)COUT * CD * 2);
    p.x_b = x_b;       p.Wih_qb = Wih_qb; p.Whh_qb = Whh_qb;
    p.Wd_qb = Wd_qb;   p.Wmu_qb = Wmu_qb; p.Wsg_qb = Wsg_qb;
    p.Wih_pb = Wih_pb; p.Whh_pb = Whh_pb; p.Wd_pb = Wd_pb;
    p.Wmu_pb = Wmu_pb; p.Wsg_pb = Wsg_pb;

    hipMemsetAsync(p.e_f0, 0, (size_t)CB * CH * 4, stream);
    hipMemsetAsync(p.d_f0, 0, (size_t)CB * CH * 4, stream);
    hipMemsetAsync(p.e_b0, 0, (size_t)CB * CH * 2, stream);
    hipMemsetAsync(p.d_b0, 0, (size_t)CB * CH * 2, stream);
    hipMemsetAsync(p.zflow, 0, (size_t)CB * CZ * 2, stream);   // slot 0 = zeros
    hipMemsetAsync(p.qbar, 0, (size_t)16 * 8 * 16 * 4, stream);
    hipMemsetAsync(p.pbar, 0, (size_t)16 * 8 * 16 * 4, stream);
    hipMemsetAsync(p.zbar, 0, (size_t)16 * 16 * 4, stream);
    hipMemsetAsync(p.pdone, 0, (size_t)16 * 16 * 4, stream);
    hipMemsetAsync(p.xcc, 0, (size_t)256 * 16 * 4, stream);
    hipMemsetAsync(p.cnt, 0, 256, stream);

    auto cvt = [&](const float* s, bf16* d, size_t n) {
        k_cvt<<<dim3((unsigned)((n / 4 + 255) / 256)), dim3(256), 0, stream>>>(s, d, (int)n);
    };
    cvt(x,      x_b,    (size_t)CB * CW * CIN);
    cvt(Wih_q,  Wih_qb, (size_t)3 * CH * CIN);
    cvt(Whh_q,  Whh_qb, (size_t)3 * CH * CH);
    cvt(Wd_q,   Wd_qb,  (size_t)CD * (CZ + CH));
    cvt(Wmu_q,  Wmu_qb, (size_t)CZ * CD);
    cvt(Wsig_q, Wsg_qb, (size_t)CZ * CD);
    cvt(Wih_p,  Wih_pb, (size_t)3 * CH * CZ);
    cvt(Whh_p,  Whh_pb, (size_t)3 * CH * CH);
    cvt(Wd_p,   Wd_pb,  (size_t)CD * CH);
    cvt(Wmu_p,  Wmu_pb, (size_t)COUT * CD);
    cvt(Wsig_p, Wsg_pb, (size_t)COUT * CD);

    mega<<<dim3(256), dim3(512), SMEM_BYTES, stream>>>(p);
}